// Round 6
// baseline (519.470 us; speedup 1.0000x reference)
//
#include <hip/hip_runtime.h>
#include <hip/hip_fp16.h>
#include <cstdint>
#include <cstddef>

using u16 = unsigned short;
using u32 = unsigned int;

typedef _Float16 half8 __attribute__((ext_vector_type(8)));
typedef float f32x4 __attribute__((ext_vector_type(4)));

static inline int cdiv(int a, int b) { return (a + b - 1) / b; }

// ===========================================================================
// prep_k: fused zero-init + f16 cast + weight panelization + rule precompute.
// ===========================================================================

__global__ void prep_k(const float* __restrict__ x, const float* __restrict__ Wr,
                       const float* __restrict__ Ws, const float* __restrict__ br,
                       const float* __restrict__ W_in, const float* __restrict__ W_h1,
                       const float* __restrict__ centers, const float* __restrict__ logsig,
                       u16* __restrict__ x16, u16* __restrict__ wcat,
                       u16* __restrict__ winp, u16* __restrict__ wh1p,
                       u16* __restrict__ pcB, float* __restrict__ pccc,
                       int* __restrict__ zerobase, int nzero,
                       int Z, int C, int Wb, int N) {
    const int bid = blockIdx.x;
    const int tid = threadIdx.x;
    if (bid < Z) {                                   // zero-init region
        int i = bid * 256 + tid;
        if (i < nzero) zerobase[i] = 0;
        return;
    }
    if (bid < Z + C) {                               // x -> f16
        size_t i = (size_t)(bid - Z) * 256 + tid;
        if (i >= (size_t)N * 32) return;
        float4 v = *(const float4*)(x + i * 4);
        union { uint2 u; _Float16 h[4]; } o;
        o.h[0] = (_Float16)v.x; o.h[1] = (_Float16)v.y;
        o.h[2] = (_Float16)v.z; o.h[3] = (_Float16)v.w;
        *(uint2*)(x16 + i * 4) = o.u;
        return;
    }
    if (bid < Z + C + Wb) {                          // wcat panels [552][256][8] x3 layers
        size_t t = (size_t)(bid - Z - C) * 256 + tid;
        const size_t PL = 552u * 256u * 8u;
        int l = (int)(t / PL);
        size_t rem = t - (size_t)l * PL;
        int kp = (int)(rem >> 11);
        int o = (int)((rem >> 3) & 255);
        int e = (int)(rem & 7);
        int k = kp * 8 + e;
        float v;
        if (k < 4096)      v = Wr[((((size_t)l * 16 + (k >> 8)) * 256) + (k & 255)) * 256 + o];
        else if (k < 4352) v = Ws[(((size_t)l * 256) + (k - 4096)) * 256 + o];
        else if (k < 4368) v = br[(((size_t)l * 16) + (k - 4352)) * 256 + o];
        else               v = 0.f;
        union { u16 u; _Float16 h; } c; c.h = (_Float16)v;
        wcat[t] = c.u;
        return;
    }
    if (bid < Z + C + Wb + 128) {                    // panelize W_in (K=128,M=256)
        size_t t = (size_t)(bid - Z - C - Wb) * 256 + tid;
        int e = (int)(t & 7), o = (int)((t >> 3) & 255);
        int kp = (int)(t >> 11);
        union { u16 u; _Float16 h; } c; c.h = (_Float16)W_in[(size_t)(kp * 8 + e) * 256 + o];
        winp[t] = c.u;
        return;
    }
    if (bid < Z + C + Wb + 256) {                    // panelize W_h1 (K=256,M=128)
        size_t t = (size_t)(bid - Z - C - Wb - 128) * 256 + tid;
        int e = (int)(t & 7), o = (int)((t >> 3) & 127);
        int kp = (int)(t >> 10);
        union { u16 u; _Float16 h; } c; c.h = (_Float16)W_h1[(size_t)(kp * 8 + e) * 128 + o];
        wh1p[t] = c.u;
        return;
    }
    {                                                // pc_build: 48 blocks (l*16+r)
        int lr = bid - (Z + C + Wb + 256);
        size_t idx = (size_t)lr * 256 + tid;
        float ls = logsig[idx];
        float inv = expf(-2.f * ls);
        float c = centers[idx];
        union { u16 u; _Float16 h; } c1, c2;
        c1.h = (_Float16)inv;
        c2.h = (_Float16)(-2.f * c * inv);
        pcB[(size_t)lr * 512 + tid] = c1.u;          // B[k][r] = inv_s2[r][k], k<256
        pcB[(size_t)lr * 512 + 256 + tid] = c2.u;    // B[256+k][r] = -2 c inv
        __shared__ float sm[256];
        sm[tid] = c * c * inv;
        __syncthreads();
        for (int s = 128; s > 0; s >>= 1) { if (tid < s) sm[tid] += sm[tid + s]; __syncthreads(); }
        if (tid == 0) pccc[lr] = sm[0];
    }
}

// ===========================================================================
// Gated CSR build: runs only if (bany[l] && !csr_done). agg_k sets csr_done.
// ===========================================================================

__global__ void deg_count_g(const int* __restrict__ dst, int* __restrict__ deg,
                            const int* __restrict__ bany, const int* __restrict__ done, int E) {
    if (*bany == 0 || *done != 0) return;
    for (int e = blockIdx.x * 256 + threadIdx.x; e < E; e += gridDim.x * 256)
        atomicAdd(&deg[dst[e]], 1);
}

__global__ void csr_scan_g(const int* __restrict__ deg, int* __restrict__ indptr,
                           int* __restrict__ cursor, float* __restrict__ deginv,
                           const int* __restrict__ bany, const int* __restrict__ done, int n) {
    if (*bany == 0 || *done != 0) return;
    const int tid = threadIdx.x;   // 1024 threads, 1 block (cold path only)
    const int chunk = (n + 1023) >> 10;
    int s0 = tid * chunk, s1 = s0 + chunk; if (s1 > n) s1 = n; if (s0 > n) s0 = n;
    int tot = 0;
    for (int i = s0; i < s1; ++i) tot += deg[i];
    __shared__ int sm[1024];
    sm[tid] = tot; __syncthreads();
    for (int off = 1; off < 1024; off <<= 1) {
        int t = (tid >= off) ? sm[tid - off] : 0;
        __syncthreads(); sm[tid] += t; __syncthreads();
    }
    int base = sm[tid] - tot;
    for (int i = s0; i < s1; ++i) {
        int d = deg[i];
        indptr[i] = base; cursor[i] = base;
        deginv[i] = 1.f / (float)(d > 1 ? d : 1);
        base += d;
    }
    if (tid == 1023) indptr[n] = sm[1023];
}

__global__ void edge_scatter_g(const int* __restrict__ src, const int* __restrict__ dst,
                               int* __restrict__ cursor, int* __restrict__ ssrc,
                               const int* __restrict__ bany, const int* __restrict__ done, int E) {
    if (*bany == 0 || *done != 0) return;
    for (int e = blockIdx.x * 256 + threadIdx.x; e < E; e += gridDim.x * 256) {
        int d = dst[e];
        int pos = atomicAdd(&cursor[d], 1);
        ssrc[pos] = src[e];
    }
}

// ===========================================================================
// MFMA membership: d = [h^2 | h] @ pcB + cc, firing = exp(-0.5 d), mu = norm.
// ===========================================================================

__launch_bounds__(256)
__global__ void memb_k(const u16* __restrict__ h16, const u16* __restrict__ pcB,
                       const float* __restrict__ pccc,
                       u16* __restrict__ mu16, int* __restrict__ bflag, int n) {
    const int lane = threadIdx.x & 63, wave = threadIdx.x >> 6;
    const int q = lane >> 4, mm = lane & 15;
    const int n0 = (blockIdx.x * 4 + wave) * 16;
    int nodeA = n0 + mm; if (nodeA >= n) nodeA = n - 1;
    const u16* hrow = h16 + (size_t)nodeA * 256;
    const u16* brow = pcB + (size_t)mm * 512;
    f32x4 acc = (f32x4){0.f, 0.f, 0.f, 0.f};
#pragma unroll
    for (int it = 0; it < 16; ++it) {
        int k = it * 32 + q * 8;
        half8 b = *(const half8*)(brow + k);
        half8 a;
        if (k < 256) {
            a = *(const half8*)(hrow + k);
            a = a * a;
        } else {
            a = *(const half8*)(hrow + (k - 256));
        }
        acc = __builtin_amdgcn_mfma_f32_16x16x32_f16(a, b, acc, 0, 0, 0);
    }
    float cc = pccc[mm];
    bool any = false;
#pragma unroll
    for (int r = 0; r < 4; ++r) {
        float d = acc[r] + cc;
        float f = expf(-0.5f * d);
        float s = f;
        s += __shfl_xor(s, 1); s += __shfl_xor(s, 2);
        s += __shfl_xor(s, 4); s += __shfl_xor(s, 8);
        int node = n0 + q * 4 + r;
        if (node < n) {
            union { u16 u; _Float16 h; } c2;
            c2.h = (_Float16)(f / (s + 1e-12f));
            mu16[(size_t)node * 16 + mm] = c2.u;
            if (s > 0.f) any = true;
        }
    }
    if (any && mm == 0) {
        atomicOr(&bflag[n0 >> 7], 1);
        atomicOr(&bflag[511], 1);
    }
}

// ===========================================================================
// Neighbor mean (grid-stride; early-exits unless this layer fired).
// ===========================================================================

__global__ void agg_k(const u16* __restrict__ h16, const int* __restrict__ indptr,
                      const int* __restrict__ ssrc, const float* __restrict__ deginv,
                      const int* __restrict__ bflag, int* __restrict__ done,
                      u16* __restrict__ agg16, int n) {
    if (bflag[511] == 0) return;
    if (blockIdx.x == 0 && threadIdx.x == 0 && *done == 0) *done = 1;
    int lane = threadIdx.x & 63, wave = threadIdx.x >> 6;
    for (int node = blockIdx.x * 4 + wave; node < n; node += gridDim.x * 4) {
        if (bflag[node >> 7] == 0) continue;
        int j0 = indptr[node], j1 = indptr[node + 1];
        float a0 = 0, a1 = 0, a2 = 0, a3 = 0;
        for (int j = j0; j < j1; ++j) {
            int sN = ssrc[j];
            union { uint2 u; _Float16 h[4]; } hv;
            hv.u = *(const uint2*)(h16 + (size_t)sN * 256 + lane * 4);
            a0 += (float)hv.h[0]; a1 += (float)hv.h[1];
            a2 += (float)hv.h[2]; a3 += (float)hv.h[3];
        }
        float di = deginv[node];
        union { uint2 u; _Float16 h[4]; } o;
        o.h[0] = (_Float16)(a0 * di); o.h[1] = (_Float16)(a1 * di);
        o.h[2] = (_Float16)(a2 * di); o.h[3] = (_Float16)(a3 * di);
        *(uint2*)(agg16 + (size_t)node * 256 + lane * 4) = o.u;
    }
}

// ===========================================================================
// Unified f16 MFMA GEMM. 128x128 tile, BK=64, 256 threads (4 waves).
// MODE 0: h16 = relu(x16 @ Winp + b_in)   (K=128)
// MODE 1: pre16 = [mu*agg | h | mu]@Wcat + b_self; BN partial sums per rowblock.
// MODE 2: q16 = relu(h16 @ Wh1p + b_h1) (K=256)
// ===========================================================================

template <int MODE, int NCHUNK>
__launch_bounds__(256, 2)
__global__ void gemm_k(const u16* __restrict__ A, const u16* __restrict__ A2,
                       const u16* __restrict__ MU, const u16* __restrict__ Bp,
                       const float* __restrict__ bias, const int* __restrict__ bflag,
                       u16* __restrict__ outH, float* __restrict__ partial,
                       int nrows, int mcols, int astride) {
    __shared__ __align__(16) u16 lA[8192];
    __shared__ __align__(16) u16 lB[8192];
    const int tid = threadIdx.x;
    const int row0 = blockIdx.x * 128;
    const int c0 = blockIdx.y * 128;
    const int lane = tid & 63;
    const int q = lane >> 4, mm = lane & 15;
    const int wave = tid >> 6;
    const int wm = wave >> 1, wn = wave & 1;

    f32x4 acc[4][4];
#pragma unroll
    for (int i = 0; i < 4; ++i)
#pragma unroll
        for (int j = 0; j < 4; ++j) acc[i][j] = (f32x4){0.f, 0.f, 0.f, 0.f};

    int cb = 0, cbEnd = NCHUNK;
    if (MODE == 1 && bflag[blockIdx.x] == 0) { cb = 64; cbEnd = 68; }  // mu==0: fuzzy+mu K exact-zero

    for (; cb < cbEnd; ++cb) {
#pragma unroll
        for (int it = 0; it < 4; ++it) {
            int idx = it * 256 + tid;
            int p = idx >> 7, col = idx & 127;
            uint4 v = *(const uint4*)(Bp + (((size_t)(cb * 8 + p)) * mcols + c0 + col) * 8);
            *(uint4*)(lB + (size_t)idx * 8) = v;
        }
#pragma unroll
        for (int it = 0; it < 4; ++it) {
            int idx = it * 256 + tid;
            int p = idx >> 7, row = idx & 127;
            int grow = row0 + row; if (grow >= nrows) grow = nrows - 1;
            uint4 v;
            if (MODE != 1) {
                v = *(const uint4*)(A + (size_t)grow * astride + cb * 64 + p * 8);
            } else {
                if (cb < 64) {
                    int r = cb >> 2;
                    int i0 = ((cb & 3) << 6) + (p << 3);
                    v = *(const uint4*)(A + (size_t)grow * 256 + i0);
                    union { u16 u; _Float16 h; } mu; mu.u = MU[(size_t)grow * 16 + r];
                    union { uint4 u4; _Float16 h[8]; } wv; wv.u4 = v;
#pragma unroll
                    for (int j = 0; j < 8; ++j) wv.h[j] = wv.h[j] * mu.h;
                    v = wv.u4;
                } else if (cb < 68) {
                    int i0 = ((cb - 64) << 6) + (p << 3);
                    v = *(const uint4*)(A2 + (size_t)grow * 256 + i0);
                } else {
                    int j0 = p << 3;
                    if (j0 < 16) v = *(const uint4*)(MU + (size_t)grow * 16 + j0);
                    else v = (uint4){0, 0, 0, 0};
                }
            }
            *(uint4*)(lA + (size_t)idx * 8) = v;
        }
        __syncthreads();
#pragma unroll
        for (int kc = 0; kc < 2; ++kc) {
            int pp = kc * 4 + q;
            half8 af[4], bf[4];
#pragma unroll
            for (int mt = 0; mt < 4; ++mt)
                af[mt] = *(const half8*)(lA + ((size_t)pp * 128 + wm * 64 + mt * 16 + mm) * 8);
#pragma unroll
            for (int nt = 0; nt < 4; ++nt)
                bf[nt] = *(const half8*)(lB + ((size_t)pp * 128 + wn * 64 + nt * 16 + mm) * 8);
#pragma unroll
            for (int mt = 0; mt < 4; ++mt)
#pragma unroll
                for (int nt = 0; nt < 4; ++nt)
                    acc[mt][nt] = __builtin_amdgcn_mfma_f32_16x16x32_f16(af[mt], bf[nt], acc[mt][nt], 0, 0, 0);
        }
        __syncthreads();
    }

    // epilogue: C/D layout col=lane&15, row=q*4+reg
    float* sbuf = (float*)lA;   // [2 wm][128 col][2 comp] floats, reuse after final sync
#pragma unroll
    for (int nt = 0; nt < 4; ++nt) {
        const int gcol = c0 + wn * 64 + nt * 16 + mm;
        float s = 0.f, ss = 0.f;
#pragma unroll
        for (int mt = 0; mt < 4; ++mt) {
#pragma unroll
            for (int r = 0; r < 4; ++r) {
                int grow = row0 + wm * 64 + mt * 16 + q * 4 + r;
                if (grow < nrows) {
                    float v = acc[mt][nt][r] + bias[gcol];
                    if (MODE != 1) v = fmaxf(v, 0.f);
                    union { u16 u; _Float16 h; } cc; cc.h = (_Float16)v;
                    outH[(size_t)grow * mcols + gcol] = cc.u;
                    if (MODE == 1) { s += v; ss += v * v; }
                }
            }
        }
        if (MODE == 1) {
            s += __shfl_xor(s, 16);  s += __shfl_xor(s, 32);
            ss += __shfl_xor(ss, 16); ss += __shfl_xor(ss, 32);
            if (q == 0) {
                int cl = wn * 64 + nt * 16 + mm;
                sbuf[(wm * 128 + cl) * 2 + 0] = s;
                sbuf[(wm * 128 + cl) * 2 + 1] = ss;
            }
        }
    }
    if (MODE == 1) {
        __syncthreads();
        int cl = tid >> 1, comp = tid & 1;
        float v = sbuf[cl * 2 + comp] + sbuf[(128 + cl) * 2 + comp];
        partial[(size_t)blockIdx.x * 512 + comp * 256 + c0 + cl] = v;
    }
}

// ===========================================================================
// bnred_k: bnsum[o] = sum_r partial[r][o], o in [0,512).  grid 2 x 256.
// ===========================================================================

__global__ void bnred_k(const float* __restrict__ partial, float* __restrict__ bnsum, int gx) {
    int o = blockIdx.x * 256 + threadIdx.x;
    float s0 = 0, s1 = 0, s2 = 0, s3 = 0;
    int r = 0;
    for (; r + 4 <= gx; r += 4) {
        s0 += partial[(size_t)r * 512 + o];
        s1 += partial[(size_t)(r + 1) * 512 + o];
        s2 += partial[(size_t)(r + 2) * 512 + o];
        s3 += partial[(size_t)(r + 3) * 512 + o];
    }
    for (; r < gx; ++r) s0 += partial[(size_t)r * 512 + o];
    bnsum[o] = (s0 + s1) + (s2 + s3);
}

// ===========================================================================
// Fused BN-finalize + residual update (f16 residual). Coeffs hoisted.
// ===========================================================================

__global__ void update_k(const u16* __restrict__ pre16, const float* __restrict__ bnsum,
                         const float* __restrict__ gamma, const float* __restrict__ beta,
                         u16* __restrict__ h16, int n) {
    int lane = threadIdx.x & 63, wave = threadIdx.x >> 6;
    int c = lane * 4;
    const float invn = 1.f / (float)n;
    float4 s4 = *(const float4*)(bnsum + c);
    float4 q4 = *(const float4*)(bnsum + 256 + c);
    float4 g4 = *(const float4*)(gamma + c);
    float4 b4 = *(const float4*)(beta + c);
    float m0 = s4.x * invn, m1 = s4.y * invn, m2 = s4.z * invn, m3 = s4.w * invn;
    float a0 = g4.x * rsqrtf(q4.x * invn - m0 * m0 + 1e-5f);
    float a1 = g4.y * rsqrtf(q4.y * invn - m1 * m1 + 1e-5f);
    float a2 = g4.z * rsqrtf(q4.z * invn - m2 * m2 + 1e-5f);
    float a3 = g4.w * rsqrtf(q4.w * invn - m3 * m3 + 1e-5f);
    float sh0 = b4.x - m0 * a0, sh1 = b4.y - m1 * a1;
    float sh2 = b4.z - m2 * a2, sh3 = b4.w - m3 * a3;

    for (int node = blockIdx.x * 4 + wave; node < n; node += gridDim.x * 4) {
        size_t base = (size_t)node * 256 + c;
        union { uint2 u; _Float16 hh[4]; } p; p.u = *(const uint2*)(pre16 + base);
        union { uint2 u; _Float16 hh[4]; } hv; hv.u = *(const uint2*)(h16 + base);
        float v0 = (float)hv.hh[0] + fmaxf((float)p.hh[0] * a0 + sh0, 0.f);
        float v1 = (float)hv.hh[1] + fmaxf((float)p.hh[1] * a1 + sh1, 0.f);
        float v2 = (float)hv.hh[2] + fmaxf((float)p.hh[2] * a2 + sh2, 0.f);
        float v3 = (float)hv.hh[3] + fmaxf((float)p.hh[3] * a3 + sh3, 0.f);
        union { uint2 u; _Float16 hh[4]; } o;
        o.hh[0] = (_Float16)v0; o.hh[1] = (_Float16)v1;
        o.hh[2] = (_Float16)v2; o.hh[3] = (_Float16)v3;
        *(uint2*)(h16 + base) = o.u;
    }
}

// ===========================================================================
// Head: logits = q16 @ W_h2 + b_h2, softmax. One thread per node, W_h2 in LDS.
// ===========================================================================

__launch_bounds__(256)
__global__ void head_k(const u16* __restrict__ q16, const float* __restrict__ Wh2,
                       const float* __restrict__ bh2, float* __restrict__ out, int n) {
    __shared__ float W[5160];
    for (int i = threadIdx.x; i < 5160; i += 256)
        W[i] = (i < 5120) ? Wh2[i] : bh2[i - 5120];
    __syncthreads();
    int node = blockIdx.x * 256 + threadIdx.x;
    if (node >= n) return;
    float acc[40];
#pragma unroll
    for (int o = 0; o < 40; ++o) acc[o] = W[5120 + o];
    const u32* qp = (const u32*)(q16 + (size_t)node * 128);
    for (int k2 = 0; k2 < 64; ++k2) {
        union { u32 u; _Float16 h[2]; } qq; qq.u = qp[k2];
        float a = (float)qq.h[0], b = (float)qq.h[1];
        const float* w0 = W + (k2 * 2) * 40;
        const float* w1 = w0 + 40;
#pragma unroll
        for (int o = 0; o < 40; ++o) acc[o] += a * w0[o] + b * w1[o];
    }
    float mx = acc[0];
#pragma unroll
    for (int o = 1; o < 40; ++o) mx = fmaxf(mx, acc[o]);
    float s = 0.f;
#pragma unroll
    for (int o = 0; o < 40; ++o) { float e = expf(acc[o] - mx); acc[o] = e; s += e; }
    float is = 1.f / s;
    float* op = out + (size_t)node * 40;
#pragma unroll
    for (int o = 0; o < 40; ++o) op[o] = acc[o] * is;
}

// ===========================================================================
// Launch
// ===========================================================================

extern "C" void kernel_launch(void* const* d_in, const int* in_sizes, int n_in,
                              void* d_out, int out_size, void* d_ws, size_t ws_size,
                              hipStream_t stream) {
    const float* x       = (const float*)d_in[0];
    const int*   ei      = (const int*)d_in[1];
    const float* W_in    = (const float*)d_in[2];
    const float* b_in    = (const float*)d_in[3];
    const float* centers = (const float*)d_in[4];
    const float* logsig  = (const float*)d_in[5];
    const float* W_rule  = (const float*)d_in[6];
    const float* b_rule  = (const float*)d_in[7];
    const float* W_self  = (const float*)d_in[8];
    const float* b_self  = (const float*)d_in[9];
    const float* gamma   = (const float*)d_in[10];
    const float* beta    = (const float*)d_in[11];
    const float* W_h1    = (const float*)d_in[12];
    const float* b_h1    = (const float*)d_in[13];
    const float* W_h2    = (const float*)d_in[14];
    const float* b_h2    = (const float*)d_in[15];

    const int N = in_sizes[0] / 128;
    const int E = in_sizes[1] / 2;
    const int* e_src = ei;
    const int* e_dst = ei + E;

    char* w = (char*)d_ws;
    size_t off = 0;
    auto alloc = [&](size_t bytes) -> void* {
        void* p = w + off;
        off = (off + bytes + 255) & ~(size_t)255;
        return p;
    };

    const int gx = cdiv(N, 128);

    u16*   x16    = (u16*)  alloc((size_t)N * 128 * 2);
    u16*   h16    = (u16*)  alloc((size_t)N * 256 * 2);
    u16*   pre16  = (u16*)  alloc((size_t)N * 256 * 2);
    u16*   agg16  = (u16*)  alloc((size_t)N * 256 * 2);
    u16*   mu16   = (u16*)  alloc((size_t)N * 16 * 2);
    u16*   q16    = (u16*)  alloc((size_t)N * 128 * 2);
    u16*   wcat   = (u16*)  alloc((size_t)3 * 552 * 256 * 8 * 2);
    u16*   winp   = (u16*)  alloc((size_t)16 * 256 * 8 * 2);
    u16*   wh1p   = (u16*)  alloc((size_t)32 * 128 * 8 * 2);
    u16*   pcB    = (u16*)  alloc((size_t)48 * 512 * 2);
    float* pccc   = (float*)alloc((size_t)48 * 4);
    int*   indptr = (int*)  alloc((size_t)(N + 1) * 4);
    int*   cursor = (int*)  alloc((size_t)N * 4);
    float* deginv = (float*)alloc((size_t)N * 4);
    int*   ssrc   = (int*)  alloc((size_t)E * 4);
    float* partial= (float*)alloc((size_t)gx * 512 * 4);
    float* bnsumA = (float*)alloc((size_t)3 * 512 * 4);
    // zero region: [deg N][bflag 3*512][csr_done pad]
    const int nzero = N + 3 * 512 + 64;
    int*   zerob  = (int*)  alloc((size_t)nzero * 4);
    int*   deg    = zerob;
    int*   bflagA = zerob + N;
    int*   done   = zerob + N + 3 * 512;

    const int Z = cdiv(nzero, 256);
    const int C = cdiv(N * 32, 256);
    const int Wb = 3 * 552 * 256 * 8 / 256;   // 13248
    const int prep_grid = Z + C + Wb + 128 + 128 + 48;

    prep_k<<<prep_grid, 256, 0, stream>>>(x, W_rule, W_self, b_rule, W_in, W_h1,
                                          centers, logsig, x16, wcat, winp, wh1p,
                                          pcB, pccc, zerob, nzero, Z, C, Wb, N);

    gemm_k<0, 2><<<dim3(gx, 2), 256, 0, stream>>>(x16, nullptr, nullptr, winp, b_in,
                                                  nullptr, h16, nullptr, N, 256, 128);
    memb_k<<<cdiv(N, 64), 256, 0, stream>>>(h16, pcB, pccc, mu16, bflagA, N);

    for (int l = 0; l < 3; ++l) {
        int* bf = bflagA + l * 512;
        int* bany = bf + 511;
        float* bns = bnsumA + l * 512;
        deg_count_g<<<1024, 256, 0, stream>>>(e_dst, deg, bany, done, E);
        csr_scan_g<<<1, 1024, 0, stream>>>(deg, indptr, cursor, deginv, bany, done, N);
        edge_scatter_g<<<1024, 256, 0, stream>>>(e_src, e_dst, cursor, ssrc, bany, done, E);
        agg_k<<<1024, 256, 0, stream>>>(h16, indptr, ssrc, deginv, bf, done, agg16, N);
        gemm_k<1, 69><<<dim3(gx, 2), 256, 0, stream>>>(agg16, h16, mu16,
                                                       wcat + (size_t)l * 552 * 256 * 8,
                                                       b_self + l * 256, bf, pre16,
                                                       partial, N, 256, 0);
        bnred_k<<<2, 256, 0, stream>>>(partial, bns, gx);
        update_k<<<3125, 256, 0, stream>>>(pre16, bns, gamma + l * 256, beta + l * 256,
                                           h16, N);
        if (l < 2)
            memb_k<<<cdiv(N, 64), 256, 0, stream>>>(h16, pcB + (size_t)(l + 1) * 16 * 512,
                                                    pccc + (l + 1) * 16, mu16,
                                                    bflagA + (l + 1) * 512, N);
    }

    gemm_k<2, 4><<<dim3(gx, 1), 256, 0, stream>>>(h16, nullptr, nullptr, wh1p, b_h1,
                                                  nullptr, q16, nullptr, N, 128, 256);
    head_k<<<cdiv(N, 256), 256, 0, stream>>>(q16, W_h2, b_h2, (float*)d_out, N);
}

// Round 7
// 490.652 us; speedup vs baseline: 1.0587x; 1.0587x over previous
//
#include <hip/hip_runtime.h>
#include <hip/hip_fp16.h>
#include <cstdint>
#include <cstddef>

using u16 = unsigned short;
using u32 = unsigned int;

typedef _Float16 half8 __attribute__((ext_vector_type(8)));
typedef float f32x4 __attribute__((ext_vector_type(4)));

static inline int cdiv(int a, int b) { return (a + b - 1) / b; }

// ===========================================================================
// prep_k: fused zero-init + f16 cast + weight panelization + rule precompute.
// ===========================================================================

__global__ void prep_k(const float* __restrict__ x, const float* __restrict__ Wr,
                       const float* __restrict__ Ws, const float* __restrict__ br,
                       const float* __restrict__ W_in, const float* __restrict__ W_h1,
                       const float* __restrict__ W_h2,
                       const float* __restrict__ centers, const float* __restrict__ logsig,
                       u16* __restrict__ x16, u16* __restrict__ wcat,
                       u16* __restrict__ winp, u16* __restrict__ wh1p,
                       u16* __restrict__ wh2p,
                       u16* __restrict__ pcB, float* __restrict__ pccc,
                       int* __restrict__ zerobase, int nzero,
                       int Z, int C, int Wb, int N) {
    const int bid = blockIdx.x;
    const int tid = threadIdx.x;
    if (bid < Z) {                                   // zero-init region
        int i = bid * 256 + tid;
        if (i < nzero) zerobase[i] = 0;
        return;
    }
    if (bid < Z + C) {                               // x -> f16
        size_t i = (size_t)(bid - Z) * 256 + tid;
        if (i >= (size_t)N * 32) return;
        float4 v = *(const float4*)(x + i * 4);
        union { uint2 u; _Float16 h[4]; } o;
        o.h[0] = (_Float16)v.x; o.h[1] = (_Float16)v.y;
        o.h[2] = (_Float16)v.z; o.h[3] = (_Float16)v.w;
        *(uint2*)(x16 + i * 4) = o.u;
        return;
    }
    if (bid < Z + C + Wb) {                          // wcat panels [552][256][8] x3 layers
        size_t t = (size_t)(bid - Z - C) * 256 + tid;
        const size_t PL = 552u * 256u * 8u;
        int l = (int)(t / PL);
        size_t rem = t - (size_t)l * PL;
        int kp = (int)(rem >> 11);
        int o = (int)((rem >> 3) & 255);
        int e = (int)(rem & 7);
        int k = kp * 8 + e;
        float v;
        if (k < 4096)      v = Wr[((((size_t)l * 16 + (k >> 8)) * 256) + (k & 255)) * 256 + o];
        else if (k < 4352) v = Ws[(((size_t)l * 256) + (k - 4096)) * 256 + o];
        else if (k < 4368) v = br[(((size_t)l * 16) + (k - 4352)) * 256 + o];
        else               v = 0.f;
        union { u16 u; _Float16 h; } c; c.h = (_Float16)v;
        wcat[t] = c.u;
        return;
    }
    if (bid < Z + C + Wb + 128) {                    // panelize W_in (K=128,M=256)
        size_t t = (size_t)(bid - Z - C - Wb) * 256 + tid;
        int e = (int)(t & 7), o = (int)((t >> 3) & 255);
        int kp = (int)(t >> 11);
        union { u16 u; _Float16 h; } c; c.h = (_Float16)W_in[(size_t)(kp * 8 + e) * 256 + o];
        winp[t] = c.u;
        return;
    }
    if (bid < Z + C + Wb + 256) {                    // panelize W_h1 (K=256,M=128)
        size_t t = (size_t)(bid - Z - C - Wb - 128) * 256 + tid;
        int e = (int)(t & 7), o = (int)((t >> 3) & 127);
        int kp = (int)(t >> 10);
        union { u16 u; _Float16 h; } c; c.h = (_Float16)W_h1[(size_t)(kp * 8 + e) * 128 + o];
        wh1p[t] = c.u;
        return;
    }
    if (bid < Z + C + Wb + 256 + 24) {               // panelize W_h2 (K=128,M=40->48 pad)
        int t = (bid - Z - C - Wb - 256) * 256 + tid; // 16*48*8 = 6144
        int e = t & 7, col = (t >> 3) % 48, p = t / 384;
        int k = p * 8 + e;
        float v = (col < 40) ? W_h2[(size_t)k * 40 + col] : 0.f;
        union { u16 u; _Float16 h; } c; c.h = (_Float16)v;
        wh2p[t] = c.u;
        return;
    }
    {                                                // pc_build: 48 blocks (l*16+r)
        int lr = bid - (Z + C + Wb + 256 + 24);
        size_t idx = (size_t)lr * 256 + tid;
        float ls = logsig[idx];
        float inv = expf(-2.f * ls);
        float c = centers[idx];
        union { u16 u; _Float16 h; } c1, c2;
        c1.h = (_Float16)inv;
        c2.h = (_Float16)(-2.f * c * inv);
        pcB[(size_t)lr * 512 + tid] = c1.u;          // B[k][r] = inv_s2[r][k], k<256
        pcB[(size_t)lr * 512 + 256 + tid] = c2.u;    // B[256+k][r] = -2 c inv
        __shared__ float sm[256];
        sm[tid] = c * c * inv;
        __syncthreads();
        for (int s = 128; s > 0; s >>= 1) { if (tid < s) sm[tid] += sm[tid + s]; __syncthreads(); }
        if (tid == 0) pccc[lr] = sm[0];
    }
}

// ===========================================================================
// Gated CSR build: runs only if (bany[l] && !csr_done). agg_k sets csr_done.
// ===========================================================================

__global__ void deg_count_g(const int* __restrict__ dst, int* __restrict__ deg,
                            const int* __restrict__ bany, const int* __restrict__ done, int E) {
    if (*bany == 0 || *done != 0) return;
    for (int e = blockIdx.x * 256 + threadIdx.x; e < E; e += gridDim.x * 256)
        atomicAdd(&deg[dst[e]], 1);
}

__global__ void csr_scan_g(const int* __restrict__ deg, int* __restrict__ indptr,
                           int* __restrict__ cursor, float* __restrict__ deginv,
                           const int* __restrict__ bany, const int* __restrict__ done, int n) {
    if (*bany == 0 || *done != 0) return;
    const int tid = threadIdx.x;   // 1024 threads, 1 block (cold path only)
    const int chunk = (n + 1023) >> 10;
    int s0 = tid * chunk, s1 = s0 + chunk; if (s1 > n) s1 = n; if (s0 > n) s0 = n;
    int tot = 0;
    for (int i = s0; i < s1; ++i) tot += deg[i];
    __shared__ int sm[1024];
    sm[tid] = tot; __syncthreads();
    for (int off = 1; off < 1024; off <<= 1) {
        int t = (tid >= off) ? sm[tid - off] : 0;
        __syncthreads(); sm[tid] += t; __syncthreads();
    }
    int base = sm[tid] - tot;
    for (int i = s0; i < s1; ++i) {
        int d = deg[i];
        indptr[i] = base; cursor[i] = base;
        deginv[i] = 1.f / (float)(d > 1 ? d : 1);
        base += d;
    }
    if (tid == 1023) indptr[n] = sm[1023];
}

__global__ void edge_scatter_g(const int* __restrict__ src, const int* __restrict__ dst,
                               int* __restrict__ cursor, int* __restrict__ ssrc,
                               const int* __restrict__ bany, const int* __restrict__ done, int E) {
    if (*bany == 0 || *done != 0) return;
    for (int e = blockIdx.x * 256 + threadIdx.x; e < E; e += gridDim.x * 256) {
        int d = dst[e];
        int pos = atomicAdd(&cursor[d], 1);
        ssrc[pos] = src[e];
    }
}

// ===========================================================================
// MFMA membership (standalone, layer 0): d = [h^2|h] @ pcB + cc; mu = norm.
// ===========================================================================

__launch_bounds__(256)
__global__ void memb_k(const u16* __restrict__ h16, const u16* __restrict__ pcB,
                       const float* __restrict__ pccc,
                       u16* __restrict__ mu16, int* __restrict__ bflag, int n) {
    const int lane = threadIdx.x & 63, wave = threadIdx.x >> 6;
    const int q = lane >> 4, mm = lane & 15;
    const int n0 = (blockIdx.x * 4 + wave) * 16;
    if (n0 >= n) return;
    int nodeA = n0 + mm; if (nodeA >= n) nodeA = n - 1;
    const u16* hrow = h16 + (size_t)nodeA * 256;
    const u16* brow = pcB + (size_t)mm * 512;
    f32x4 acc = (f32x4){0.f, 0.f, 0.f, 0.f};
#pragma unroll
    for (int it = 0; it < 16; ++it) {
        int k = it * 32 + q * 8;
        half8 b = *(const half8*)(brow + k);
        half8 a;
        if (k < 256) {
            a = *(const half8*)(hrow + k);
            a = a * a;
        } else {
            a = *(const half8*)(hrow + (k - 256));
        }
        acc = __builtin_amdgcn_mfma_f32_16x16x32_f16(a, b, acc, 0, 0, 0);
    }
    float cc = pccc[mm];
    bool any = false;
#pragma unroll
    for (int r = 0; r < 4; ++r) {
        float d = acc[r] + cc;
        float f = expf(-0.5f * d);
        float s = f;
        s += __shfl_xor(s, 1); s += __shfl_xor(s, 2);
        s += __shfl_xor(s, 4); s += __shfl_xor(s, 8);
        int node = n0 + q * 4 + r;
        if (node < n) {
            union { u16 u; _Float16 h; } c2;
            c2.h = (_Float16)(f / (s + 1e-12f));
            mu16[(size_t)node * 16 + mm] = c2.u;
            if (s > 0.f) any = true;
        }
    }
    if (any && mm == 0) {
        atomicOr(&bflag[n0 >> 7], 1);
        atomicOr(&bflag[511], 1);
    }
}

// ===========================================================================
// Neighbor mean (grid-stride; early-exits unless this layer fired).
// ===========================================================================

__global__ void agg_k(const u16* __restrict__ h16, const int* __restrict__ indptr,
                      const int* __restrict__ ssrc, const float* __restrict__ deginv,
                      const int* __restrict__ bflag, int* __restrict__ done,
                      u16* __restrict__ agg16, int n) {
    if (bflag[511] == 0) return;
    if (blockIdx.x == 0 && threadIdx.x == 0 && *done == 0) *done = 1;
    int lane = threadIdx.x & 63, wave = threadIdx.x >> 6;
    for (int node = blockIdx.x * 4 + wave; node < n; node += gridDim.x * 4) {
        if (bflag[node >> 7] == 0) continue;
        int j0 = indptr[node], j1 = indptr[node + 1];
        float a0 = 0, a1 = 0, a2 = 0, a3 = 0;
        for (int j = j0; j < j1; ++j) {
            int sN = ssrc[j];
            union { uint2 u; _Float16 h[4]; } hv;
            hv.u = *(const uint2*)(h16 + (size_t)sN * 256 + lane * 4);
            a0 += (float)hv.h[0]; a1 += (float)hv.h[1];
            a2 += (float)hv.h[2]; a3 += (float)hv.h[3];
        }
        float di = deginv[node];
        union { uint2 u; _Float16 h[4]; } o;
        o.h[0] = (_Float16)(a0 * di); o.h[1] = (_Float16)(a1 * di);
        o.h[2] = (_Float16)(a2 * di); o.h[3] = (_Float16)(a3 * di);
        *(uint2*)(agg16 + (size_t)node * 256 + lane * 4) = o.u;
    }
}

// ===========================================================================
// Unified f16 MFMA GEMM. 128x128 tile, BK=64, 256 threads (4 waves).
// MODE 0: h16 = relu(x16 @ Winp + b_in)   (K=128)
// MODE 1: pre16 = [mu*agg | h | mu]@Wcat + b_self; BN partial sums per rowblock.
// MODE 2: q16 = relu(h16 @ Wh1p + b_h1) (K=256)
// ===========================================================================

template <int MODE, int NCHUNK>
__launch_bounds__(256, 2)
__global__ void gemm_k(const u16* __restrict__ A, const u16* __restrict__ A2,
                       const u16* __restrict__ MU, const u16* __restrict__ Bp,
                       const float* __restrict__ bias, const int* __restrict__ bflag,
                       u16* __restrict__ outH, float* __restrict__ partial,
                       int nrows, int mcols, int astride) {
    __shared__ __align__(16) u16 lA[8192];
    __shared__ __align__(16) u16 lB[8192];
    const int tid = threadIdx.x;
    const int row0 = blockIdx.x * 128;
    const int c0 = blockIdx.y * 128;
    const int lane = tid & 63;
    const int q = lane >> 4, mm = lane & 15;
    const int wave = tid >> 6;
    const int wm = wave >> 1, wn = wave & 1;

    f32x4 acc[4][4];
#pragma unroll
    for (int i = 0; i < 4; ++i)
#pragma unroll
        for (int j = 0; j < 4; ++j) acc[i][j] = (f32x4){0.f, 0.f, 0.f, 0.f};

    int cb = 0, cbEnd = NCHUNK;
    if (MODE == 1 && bflag[blockIdx.x] == 0) { cb = 64; cbEnd = 68; }  // mu==0: fuzzy+mu K exact-zero

    for (; cb < cbEnd; ++cb) {
#pragma unroll
        for (int it = 0; it < 4; ++it) {
            int idx = it * 256 + tid;
            int p = idx >> 7, col = idx & 127;
            uint4 v = *(const uint4*)(Bp + (((size_t)(cb * 8 + p)) * mcols + c0 + col) * 8);
            *(uint4*)(lB + (size_t)idx * 8) = v;
        }
#pragma unroll
        for (int it = 0; it < 4; ++it) {
            int idx = it * 256 + tid;
            int p = idx >> 7, row = idx & 127;
            int grow = row0 + row; if (grow >= nrows) grow = nrows - 1;
            uint4 v;
            if (MODE != 1) {
                v = *(const uint4*)(A + (size_t)grow * astride + cb * 64 + p * 8);
            } else {
                if (cb < 64) {
                    int r = cb >> 2;
                    int i0 = ((cb & 3) << 6) + (p << 3);
                    v = *(const uint4*)(A + (size_t)grow * 256 + i0);
                    union { u16 u; _Float16 h; } mu; mu.u = MU[(size_t)grow * 16 + r];
                    union { uint4 u4; _Float16 h[8]; } wv; wv.u4 = v;
#pragma unroll
                    for (int j = 0; j < 8; ++j) wv.h[j] = wv.h[j] * mu.h;
                    v = wv.u4;
                } else if (cb < 68) {
                    int i0 = ((cb - 64) << 6) + (p << 3);
                    v = *(const uint4*)(A2 + (size_t)grow * 256 + i0);
                } else {
                    int j0 = p << 3;
                    if (j0 < 16) v = *(const uint4*)(MU + (size_t)grow * 16 + j0);
                    else v = (uint4){0, 0, 0, 0};
                }
            }
            *(uint4*)(lA + (size_t)idx * 8) = v;
        }
        __syncthreads();
#pragma unroll
        for (int kc = 0; kc < 2; ++kc) {
            int pp = kc * 4 + q;
            half8 af[4], bf[4];
#pragma unroll
            for (int mt = 0; mt < 4; ++mt)
                af[mt] = *(const half8*)(lA + ((size_t)pp * 128 + wm * 64 + mt * 16 + mm) * 8);
#pragma unroll
            for (int nt = 0; nt < 4; ++nt)
                bf[nt] = *(const half8*)(lB + ((size_t)pp * 128 + wn * 64 + nt * 16 + mm) * 8);
#pragma unroll
            for (int mt = 0; mt < 4; ++mt)
#pragma unroll
                for (int nt = 0; nt < 4; ++nt)
                    acc[mt][nt] = __builtin_amdgcn_mfma_f32_16x16x32_f16(af[mt], bf[nt], acc[mt][nt], 0, 0, 0);
        }
        __syncthreads();
    }

    // epilogue: C/D layout col=lane&15, row=q*4+reg
    float* sbuf = (float*)lA;   // [2 wm][128 col][2 comp] floats, reuse after final sync
#pragma unroll
    for (int nt = 0; nt < 4; ++nt) {
        const int gcol = c0 + wn * 64 + nt * 16 + mm;
        float s = 0.f, ss = 0.f;
#pragma unroll
        for (int mt = 0; mt < 4; ++mt) {
#pragma unroll
            for (int r = 0; r < 4; ++r) {
                int grow = row0 + wm * 64 + mt * 16 + q * 4 + r;
                if (grow < nrows) {
                    float v = acc[mt][nt][r] + bias[gcol];
                    if (MODE != 1) v = fmaxf(v, 0.f);
                    union { u16 u; _Float16 h; } cc; cc.h = (_Float16)v;
                    outH[(size_t)grow * mcols + gcol] = cc.u;
                    if (MODE == 1) { s += v; ss += v * v; }
                }
            }
        }
        if (MODE == 1) {
            s += __shfl_xor(s, 16);  s += __shfl_xor(s, 32);
            ss += __shfl_xor(ss, 16); ss += __shfl_xor(ss, 32);
            if (q == 0) {
                int cl = wn * 64 + nt * 16 + mm;
                sbuf[(wm * 128 + cl) * 2 + 0] = s;
                sbuf[(wm * 128 + cl) * 2 + 1] = ss;
            }
        }
    }
    if (MODE == 1) {
        __syncthreads();
        int cl = tid >> 1, comp = tid & 1;
        float v = sbuf[cl * 2 + comp] + sbuf[(128 + cl) * 2 + comp];
        partial[(size_t)blockIdx.x * 512 + comp * 256 + c0 + cl] = v;
    }
}

// ===========================================================================
// bnred_k: bnsum[o] = sum_r partial[r][o], o in [0,512).  grid 2 x 256.
// ===========================================================================

__global__ void bnred_k(const float* __restrict__ partial, float* __restrict__ bnsum, int gx) {
    int o = blockIdx.x * 256 + threadIdx.x;
    float s0 = 0, s1 = 0, s2 = 0, s3 = 0;
    int r = 0;
    for (; r + 4 <= gx; r += 4) {
        s0 += partial[(size_t)r * 512 + o];
        s1 += partial[(size_t)(r + 1) * 512 + o];
        s2 += partial[(size_t)(r + 2) * 512 + o];
        s3 += partial[(size_t)(r + 3) * 512 + o];
    }
    for (; r < gx; ++r) s0 += partial[(size_t)r * 512 + o];
    bnsum[o] = (s0 + s1) + (s2 + s3);
}

// ===========================================================================
// Fused BN-finalize + residual update + (optional) next-layer membership.
// Lane (q,mm) owns node n0+mm, channels {b*32+q*8..+7} — the MFMA A footprint.
// ===========================================================================

template <int DOMEMB>
__launch_bounds__(256)
__global__ void updmemb_k(const u16* __restrict__ pre16, const float* __restrict__ bnsum,
                          const float* __restrict__ gamma, const float* __restrict__ beta,
                          u16* __restrict__ h16,
                          const u16* __restrict__ pcB, const float* __restrict__ pccc,
                          u16* __restrict__ mu16, int* __restrict__ bflag, int n) {
    const int lane = threadIdx.x & 63, wave = threadIdx.x >> 6;
    const int q = lane >> 4, mm = lane & 15;
    const int n0 = (blockIdx.x * 4 + wave) * 16;
    if (n0 >= n) return;
    const int node = n0 + mm;
    const bool valid = node < n;
    const int nodeC = valid ? node : n - 1;
    const float invn = 1.f / (float)n;
    const size_t base = (size_t)nodeC * 256 + q * 8;

    half8 v16[8];
#pragma unroll
    for (int b = 0; b < 8; ++b) {
        int c = b * 32 + q * 8;
        float4 sA = *(const float4*)(bnsum + c);
        float4 sB = *(const float4*)(bnsum + c + 4);
        float4 qA = *(const float4*)(bnsum + 256 + c);
        float4 qB = *(const float4*)(bnsum + 256 + c + 4);
        float4 gA = *(const float4*)(gamma + c);
        float4 gB = *(const float4*)(gamma + c + 4);
        float4 bA = *(const float4*)(beta + c);
        float4 bB = *(const float4*)(beta + c + 4);
        float sarr[8] = {sA.x, sA.y, sA.z, sA.w, sB.x, sB.y, sB.z, sB.w};
        float qarr[8] = {qA.x, qA.y, qA.z, qA.w, qB.x, qB.y, qB.z, qB.w};
        float garr[8] = {gA.x, gA.y, gA.z, gA.w, gB.x, gB.y, gB.z, gB.w};
        float barr[8] = {bA.x, bA.y, bA.z, bA.w, bB.x, bB.y, bB.z, bB.w};
        union { uint4 u; _Float16 hh[8]; } p, hv, o;
        p.u  = *(const uint4*)(pre16 + base + b * 32);
        hv.u = *(const uint4*)(h16 + base + b * 32);
#pragma unroll
        for (int j = 0; j < 8; ++j) {
            float m = sarr[j] * invn;
            float al = garr[j] * rsqrtf(qarr[j] * invn - m * m + 1e-5f);
            float sh = barr[j] - m * al;
            float v = (float)hv.hh[j] + fmaxf((float)p.hh[j] * al + sh, 0.f);
            o.hh[j] = (_Float16)v;
        }
        if (valid) *(uint4*)(h16 + base + b * 32) = o.u;
        v16[b] = *(half8*)&o;
    }

    if (DOMEMB) {
        const u16* brow = pcB + (size_t)mm * 512;
        f32x4 acc = (f32x4){0.f, 0.f, 0.f, 0.f};
#pragma unroll
        for (int it = 0; it < 16; ++it) {
            half8 a = v16[it & 7];
            if (it < 8) a = a * a;
            half8 bb = *(const half8*)(brow + it * 32 + q * 8);
            acc = __builtin_amdgcn_mfma_f32_16x16x32_f16(a, bb, acc, 0, 0, 0);
        }
        float cc = pccc[mm];
        bool any = false;
#pragma unroll
        for (int r = 0; r < 4; ++r) {
            float d = acc[r] + cc;
            float f = expf(-0.5f * d);
            float s = f;
            s += __shfl_xor(s, 1); s += __shfl_xor(s, 2);
            s += __shfl_xor(s, 4); s += __shfl_xor(s, 8);
            int nd = n0 + q * 4 + r;
            if (nd < n) {
                union { u16 u; _Float16 h; } c2;
                c2.h = (_Float16)(f / (s + 1e-12f));
                mu16[(size_t)nd * 16 + mm] = c2.u;
                if (s > 0.f) any = true;
            }
        }
        if (any && mm == 0) {
            atomicOr(&bflag[n0 >> 7], 1);
            atomicOr(&bflag[511], 1);
        }
    }
}

// ===========================================================================
// MFMA head: logits = q16 @ Wh2p + b_h2 (40 cols padded to 48), softmax, f32 out.
// Per wave: 16 nodes; 12 MFMAs (K=128, 3 col-tiles). Softmax over mm lanes.
// ===========================================================================

__launch_bounds__(256)
__global__ void head2_k(const u16* __restrict__ q16, const u16* __restrict__ wh2p,
                        const float* __restrict__ bh2, float* __restrict__ out, int n) {
    const int lane = threadIdx.x & 63, wave = threadIdx.x >> 6;
    const int q = lane >> 4, mm = lane & 15;
    const int n0 = (blockIdx.x * 4 + wave) * 16;
    if (n0 >= n) return;
    int nodeA = n0 + mm; if (nodeA >= n) nodeA = n - 1;
    const u16* qrow = q16 + (size_t)nodeA * 128;
    f32x4 acc[3];
#pragma unroll
    for (int t = 0; t < 3; ++t) acc[t] = (f32x4){0.f, 0.f, 0.f, 0.f};
#pragma unroll
    for (int c = 0; c < 4; ++c) {
        half8 a = *(const half8*)(qrow + c * 32 + q * 8);
#pragma unroll
        for (int t = 0; t < 3; ++t) {
            half8 b = *(const half8*)(wh2p + ((size_t)(c * 4 + q) * 48 + t * 16 + mm) * 8);
            acc[t] = __builtin_amdgcn_mfma_f32_16x16x32_f16(a, b, acc[t], 0, 0, 0);
        }
    }
    const bool c2ok = (mm < 8);                 // col 32+mm < 40
    float b0 = bh2[mm], b1 = bh2[16 + mm];
    float b2 = c2ok ? bh2[32 + mm] : 0.f;
#pragma unroll
    for (int r = 0; r < 4; ++r) {
        int node = n0 + q * 4 + r;
        float v0 = acc[0][r] + b0;
        float v1 = acc[1][r] + b1;
        float v2 = c2ok ? (acc[2][r] + b2) : -3e38f;
        float m = fmaxf(fmaxf(v0, v1), v2);
        m = fmaxf(m, __shfl_xor(m, 1)); m = fmaxf(m, __shfl_xor(m, 2));
        m = fmaxf(m, __shfl_xor(m, 4)); m = fmaxf(m, __shfl_xor(m, 8));
        float e0 = expf(v0 - m), e1 = expf(v1 - m);
        float e2 = c2ok ? expf(v2 - m) : 0.f;
        float s = e0 + e1 + e2;
        s += __shfl_xor(s, 1); s += __shfl_xor(s, 2);
        s += __shfl_xor(s, 4); s += __shfl_xor(s, 8);
        float is = 1.f / s;
        if (node < n) {
            float* op = out + (size_t)node * 40;
            op[mm] = e0 * is;
            op[16 + mm] = e1 * is;
            if (c2ok) op[32 + mm] = e2 * is;
        }
    }
}

// ===========================================================================
// Launch
// ===========================================================================

extern "C" void kernel_launch(void* const* d_in, const int* in_sizes, int n_in,
                              void* d_out, int out_size, void* d_ws, size_t ws_size,
                              hipStream_t stream) {
    const float* x       = (const float*)d_in[0];
    const int*   ei      = (const int*)d_in[1];
    const float* W_in    = (const float*)d_in[2];
    const float* b_in    = (const float*)d_in[3];
    const float* centers = (const float*)d_in[4];
    const float* logsig  = (const float*)d_in[5];
    const float* W_rule  = (const float*)d_in[6];
    const float* b_rule  = (const float*)d_in[7];
    const float* W_self  = (const float*)d_in[8];
    const float* b_self  = (const float*)d_in[9];
    const float* gamma   = (const float*)d_in[10];
    const float* beta    = (const float*)d_in[11];
    const float* W_h1    = (const float*)d_in[12];
    const float* b_h1    = (const float*)d_in[13];
    const float* W_h2    = (const float*)d_in[14];
    const float* b_h2    = (const float*)d_in[15];

    const int N = in_sizes[0] / 128;
    const int E = in_sizes[1] / 2;
    const int* e_src = ei;
    const int* e_dst = ei + E;

    char* w = (char*)d_ws;
    size_t off = 0;
    auto alloc = [&](size_t bytes) -> void* {
        void* p = w + off;
        off = (off + bytes + 255) & ~(size_t)255;
        return p;
    };

    const int gx = cdiv(N, 128);

    u16*   x16    = (u16*)  alloc((size_t)N * 128 * 2);
    u16*   h16    = (u16*)  alloc((size_t)N * 256 * 2);
    u16*   pre16  = (u16*)  alloc((size_t)N * 256 * 2);
    u16*   agg16  = (u16*)  alloc((size_t)N * 256 * 2);
    u16*   mu16   = (u16*)  alloc((size_t)N * 16 * 2);
    u16*   q16    = (u16*)  alloc((size_t)N * 128 * 2);
    u16*   wcat   = (u16*)  alloc((size_t)3 * 552 * 256 * 8 * 2);
    u16*   winp   = (u16*)  alloc((size_t)16 * 256 * 8 * 2);
    u16*   wh1p   = (u16*)  alloc((size_t)32 * 128 * 8 * 2);
    u16*   wh2p   = (u16*)  alloc((size_t)16 * 48 * 8 * 2);
    u16*   pcB    = (u16*)  alloc((size_t)48 * 512 * 2);
    float* pccc   = (float*)alloc((size_t)48 * 4);
    int*   indptr = (int*)  alloc((size_t)(N + 1) * 4);
    int*   cursor = (int*)  alloc((size_t)N * 4);
    float* deginv = (float*)alloc((size_t)N * 4);
    int*   ssrc   = (int*)  alloc((size_t)E * 4);
    float* partial= (float*)alloc((size_t)gx * 512 * 4);
    float* bnsumA = (float*)alloc((size_t)3 * 512 * 4);
    // zero region: [deg N][bflag 3*512][csr_done pad]
    const int nzero = N + 3 * 512 + 64;
    int*   zerob  = (int*)  alloc((size_t)nzero * 4);
    int*   deg    = zerob;
    int*   bflagA = zerob + N;
    int*   done   = zerob + N + 3 * 512;

    const int Z = cdiv(nzero, 256);
    const int C = cdiv(N * 32, 256);
    const int Wb = 3 * 552 * 256 * 8 / 256;   // 13248
    const int prep_grid = Z + C + Wb + 128 + 128 + 24 + 48;

    prep_k<<<prep_grid, 256, 0, stream>>>(x, W_rule, W_self, b_rule, W_in, W_h1, W_h2,
                                          centers, logsig, x16, wcat, winp, wh1p, wh2p,
                                          pcB, pccc, zerob, nzero, Z, C, Wb, N);

    gemm_k<0, 2><<<dim3(gx, 2), 256, 0, stream>>>(x16, nullptr, nullptr, winp, b_in,
                                                  nullptr, h16, nullptr, N, 256, 128);
    memb_k<<<cdiv(N, 64), 256, 0, stream>>>(h16, pcB, pccc, mu16, bflagA, N);

    for (int l = 0; l < 3; ++l) {
        int* bf = bflagA + l * 512;
        int* bany = bf + 511;
        float* bns = bnsumA + l * 512;
        deg_count_g<<<1024, 256, 0, stream>>>(e_dst, deg, bany, done, E);
        csr_scan_g<<<1, 1024, 0, stream>>>(deg, indptr, cursor, deginv, bany, done, N);
        edge_scatter_g<<<1024, 256, 0, stream>>>(e_src, e_dst, cursor, ssrc, bany, done, E);
        agg_k<<<1024, 256, 0, stream>>>(h16, indptr, ssrc, deginv, bf, done, agg16, N);
        gemm_k<1, 69><<<dim3(gx, 2), 256, 0, stream>>>(agg16, h16, mu16,
                                                       wcat + (size_t)l * 552 * 256 * 8,
                                                       b_self + l * 256, bf, pre16,
                                                       partial, N, 256, 0);
        bnred_k<<<2, 256, 0, stream>>>(partial, bns, gx);
        if (l < 2) {
            updmemb_k<1><<<cdiv(N, 64), 256, 0, stream>>>(pre16, bns, gamma + l * 256,
                                                          beta + l * 256, h16,
                                                          pcB + (size_t)(l + 1) * 16 * 512,
                                                          pccc + (l + 1) * 16, mu16,
                                                          bflagA + (l + 1) * 512, N);
        } else {
            updmemb_k<0><<<cdiv(N, 64), 256, 0, stream>>>(pre16, bns, gamma + l * 256,
                                                          beta + l * 256, h16,
                                                          nullptr, nullptr, nullptr,
                                                          nullptr, N);
        }
    }

    gemm_k<2, 4><<<dim3(gx, 1), 256, 0, stream>>>(h16, nullptr, nullptr, wh1p, b_h1,
                                                  nullptr, q16, nullptr, N, 128, 256);
    head2_k<<<cdiv(N, 64), 256, 0, stream>>>(q16, wh2p, b_h2, (float*)d_out, N);
}

// Round 8
// 419.438 us; speedup vs baseline: 1.2385x; 1.1698x over previous
//
#include <hip/hip_runtime.h>
#include <hip/hip_fp16.h>
#include <cstdint>
#include <cstddef>

using u16 = unsigned short;
using u32 = unsigned int;

typedef _Float16 half8 __attribute__((ext_vector_type(8)));
typedef float f32x4 __attribute__((ext_vector_type(4)));

static inline int cdiv(int a, int b) { return (a + b - 1) / b; }

// ===========================================================================
// prep_k: fused zero-init + f16 cast + weight panelization + rule precompute.
// ===========================================================================

__global__ void prep_k(const float* __restrict__ x, const float* __restrict__ Wr,
                       const float* __restrict__ Ws, const float* __restrict__ br,
                       const float* __restrict__ W_in, const float* __restrict__ W_h1,
                       const float* __restrict__ W_h2,
                       const float* __restrict__ centers, const float* __restrict__ logsig,
                       u16* __restrict__ x16, u16* __restrict__ wcat,
                       u16* __restrict__ winp, u16* __restrict__ wh1p,
                       u16* __restrict__ wh2p,
                       u16* __restrict__ pcB, float* __restrict__ pccc,
                       int* __restrict__ zerobase, int nzero,
                       int Z, int C, int Wb, int N) {
    const int bid = blockIdx.x;
    const int tid = threadIdx.x;
    if (bid < Z) {                                   // zero-init region
        int i = bid * 256 + tid;
        if (i < nzero) zerobase[i] = 0;
        return;
    }
    if (bid < Z + C) {                               // x -> f16
        size_t i = (size_t)(bid - Z) * 256 + tid;
        if (i >= (size_t)N * 32) return;
        float4 v = *(const float4*)(x + i * 4);
        union { uint2 u; _Float16 h[4]; } o;
        o.h[0] = (_Float16)v.x; o.h[1] = (_Float16)v.y;
        o.h[2] = (_Float16)v.z; o.h[3] = (_Float16)v.w;
        *(uint2*)(x16 + i * 4) = o.u;
        return;
    }
    if (bid < Z + C + Wb) {                          // wcat panels [552][256][8] x3 layers
        size_t t = (size_t)(bid - Z - C) * 256 + tid;
        const size_t PL = 552u * 256u * 8u;
        int l = (int)(t / PL);
        size_t rem = t - (size_t)l * PL;
        int kp = (int)(rem >> 11);
        int o = (int)((rem >> 3) & 255);
        int e = (int)(rem & 7);
        int k = kp * 8 + e;
        float v;
        if (k < 4096)      v = Wr[((((size_t)l * 16 + (k >> 8)) * 256) + (k & 255)) * 256 + o];
        else if (k < 4352) v = Ws[(((size_t)l * 256) + (k - 4096)) * 256 + o];
        else if (k < 4368) v = br[(((size_t)l * 16) + (k - 4352)) * 256 + o];
        else               v = 0.f;
        union { u16 u; _Float16 h; } c; c.h = (_Float16)v;
        wcat[t] = c.u;
        return;
    }
    if (bid < Z + C + Wb + 128) {                    // panelize W_in (K=128,M=256)
        size_t t = (size_t)(bid - Z - C - Wb) * 256 + tid;
        int e = (int)(t & 7), o = (int)((t >> 3) & 255);
        int kp = (int)(t >> 11);
        union { u16 u; _Float16 h; } c; c.h = (_Float16)W_in[(size_t)(kp * 8 + e) * 256 + o];
        winp[t] = c.u;
        return;
    }
    if (bid < Z + C + Wb + 256) {                    // panelize W_h1 (K=256,M=128)
        size_t t = (size_t)(bid - Z - C - Wb - 128) * 256 + tid;
        int e = (int)(t & 7), o = (int)((t >> 3) & 127);
        int kp = (int)(t >> 10);
        union { u16 u; _Float16 h; } c; c.h = (_Float16)W_h1[(size_t)(kp * 8 + e) * 128 + o];
        wh1p[t] = c.u;
        return;
    }
    if (bid < Z + C + Wb + 256 + 24) {               // panelize W_h2 (K=128,M=40->48 pad)
        int t = (bid - Z - C - Wb - 256) * 256 + tid; // 16*48*8 = 6144
        int e = t & 7, col = (t >> 3) % 48, p = t / 384;
        int k = p * 8 + e;
        float v = (col < 40) ? W_h2[(size_t)k * 40 + col] : 0.f;
        union { u16 u; _Float16 h; } c; c.h = (_Float16)v;
        wh2p[t] = c.u;
        return;
    }
    {                                                // pc_build: 48 blocks (l*16+r)
        int lr = bid - (Z + C + Wb + 256 + 24);
        size_t idx = (size_t)lr * 256 + tid;
        float ls = logsig[idx];
        float inv = expf(-2.f * ls);
        float c = centers[idx];
        union { u16 u; _Float16 h; } c1, c2;
        c1.h = (_Float16)inv;
        c2.h = (_Float16)(-2.f * c * inv);
        pcB[(size_t)lr * 512 + tid] = c1.u;          // B[k][r] = inv_s2[r][k], k<256
        pcB[(size_t)lr * 512 + 256 + tid] = c2.u;    // B[256+k][r] = -2 c inv
        __shared__ float sm[256];
        sm[tid] = c * c * inv;
        __syncthreads();
        for (int s = 128; s > 0; s >>= 1) { if (tid < s) sm[tid] += sm[tid + s]; __syncthreads(); }
        if (tid == 0) pccc[lr] = sm[0];
    }
}

// ===========================================================================
// Gated CSR build: runs only if (bany[l] && !csr_done). agg_k sets csr_done.
// ===========================================================================

__global__ void deg_count_g(const int* __restrict__ dst, int* __restrict__ deg,
                            const int* __restrict__ bany, const int* __restrict__ done, int E) {
    if (*bany == 0 || *done != 0) return;
    for (int e = blockIdx.x * 256 + threadIdx.x; e < E; e += gridDim.x * 256)
        atomicAdd(&deg[dst[e]], 1);
}

__global__ void csr_scan_g(const int* __restrict__ deg, int* __restrict__ indptr,
                           int* __restrict__ cursor, float* __restrict__ deginv,
                           const int* __restrict__ bany, const int* __restrict__ done, int n) {
    if (*bany == 0 || *done != 0) return;
    const int tid = threadIdx.x;   // 1024 threads, 1 block (cold path only)
    const int chunk = (n + 1023) >> 10;
    int s0 = tid * chunk, s1 = s0 + chunk; if (s1 > n) s1 = n; if (s0 > n) s0 = n;
    int tot = 0;
    for (int i = s0; i < s1; ++i) tot += deg[i];
    __shared__ int sm[1024];
    sm[tid] = tot; __syncthreads();
    for (int off = 1; off < 1024; off <<= 1) {
        int t = (tid >= off) ? sm[tid - off] : 0;
        __syncthreads(); sm[tid] += t; __syncthreads();
    }
    int base = sm[tid] - tot;
    for (int i = s0; i < s1; ++i) {
        int d = deg[i];
        indptr[i] = base; cursor[i] = base;
        deginv[i] = 1.f / (float)(d > 1 ? d : 1);
        base += d;
    }
    if (tid == 1023) indptr[n] = sm[1023];
}

__global__ void edge_scatter_g(const int* __restrict__ src, const int* __restrict__ dst,
                               int* __restrict__ cursor, int* __restrict__ ssrc,
                               const int* __restrict__ bany, const int* __restrict__ done, int E) {
    if (*bany == 0 || *done != 0) return;
    for (int e = blockIdx.x * 256 + threadIdx.x; e < E; e += gridDim.x * 256) {
        int d = dst[e];
        int pos = atomicAdd(&cursor[d], 1);
        ssrc[pos] = src[e];
    }
}

// ===========================================================================
// MFMA membership (standalone, layer 0): d = [h^2|h] @ pcB + cc; mu = norm.
// ===========================================================================

__launch_bounds__(256)
__global__ void memb_k(const u16* __restrict__ h16, const u16* __restrict__ pcB,
                       const float* __restrict__ pccc,
                       u16* __restrict__ mu16, int* __restrict__ bflag, int n) {
    const int lane = threadIdx.x & 63, wave = threadIdx.x >> 6;
    const int q = lane >> 4, mm = lane & 15;
    const int n0 = (blockIdx.x * 4 + wave) * 16;
    if (n0 >= n) return;
    int nodeA = n0 + mm; if (nodeA >= n) nodeA = n - 1;
    const u16* hrow = h16 + (size_t)nodeA * 256;
    const u16* brow = pcB + (size_t)mm * 512;
    f32x4 acc = (f32x4){0.f, 0.f, 0.f, 0.f};
#pragma unroll
    for (int it = 0; it < 16; ++it) {
        int k = it * 32 + q * 8;
        half8 b = *(const half8*)(brow + k);
        half8 a;
        if (k < 256) {
            a = *(const half8*)(hrow + k);
            a = a * a;
        } else {
            a = *(const half8*)(hrow + (k - 256));
        }
        acc = __builtin_amdgcn_mfma_f32_16x16x32_f16(a, b, acc, 0, 0, 0);
    }
    float cc = pccc[mm];
    bool any = false;
#pragma unroll
    for (int r = 0; r < 4; ++r) {
        float d = acc[r] + cc;
        float f = expf(-0.5f * d);
        float s = f;
        s += __shfl_xor(s, 1); s += __shfl_xor(s, 2);
        s += __shfl_xor(s, 4); s += __shfl_xor(s, 8);
        int node = n0 + q * 4 + r;
        if (node < n) {
            union { u16 u; _Float16 h; } c2;
            c2.h = (_Float16)(f / (s + 1e-12f));
            mu16[(size_t)node * 16 + mm] = c2.u;
            if (s > 0.f) any = true;
        }
    }
    if (any && mm == 0) {
        atomicOr(&bflag[n0 >> 7], 1);
        atomicOr(&bflag[511], 1);
    }
}

// ===========================================================================
// Neighbor mean (grid-stride; early-exits unless this layer fired).
// ===========================================================================

__global__ void agg_k(const u16* __restrict__ h16, const int* __restrict__ indptr,
                      const int* __restrict__ ssrc, const float* __restrict__ deginv,
                      const int* __restrict__ bflag, int* __restrict__ done,
                      u16* __restrict__ agg16, int n) {
    if (bflag[511] == 0) return;
    if (blockIdx.x == 0 && threadIdx.x == 0 && *done == 0) *done = 1;
    int lane = threadIdx.x & 63, wave = threadIdx.x >> 6;
    for (int node = blockIdx.x * 4 + wave; node < n; node += gridDim.x * 4) {
        if (bflag[node >> 7] == 0) continue;
        int j0 = indptr[node], j1 = indptr[node + 1];
        float a0 = 0, a1 = 0, a2 = 0, a3 = 0;
        for (int j = j0; j < j1; ++j) {
            int sN = ssrc[j];
            union { uint2 u; _Float16 h[4]; } hv;
            hv.u = *(const uint2*)(h16 + (size_t)sN * 256 + lane * 4);
            a0 += (float)hv.h[0]; a1 += (float)hv.h[1];
            a2 += (float)hv.h[2]; a3 += (float)hv.h[3];
        }
        float di = deginv[node];
        union { uint2 u; _Float16 h[4]; } o;
        o.h[0] = (_Float16)(a0 * di); o.h[1] = (_Float16)(a1 * di);
        o.h[2] = (_Float16)(a2 * di); o.h[3] = (_Float16)(a3 * di);
        *(uint2*)(agg16 + (size_t)node * 256 + lane * 4) = o.u;
    }
}

// ===========================================================================
// Unified f16 MFMA GEMM. 128x128 tile, BK=64, 256 threads (4 waves).
// MODE 0: h16 = relu(x16 @ Winp + b_in)   (K=128)
// MODE 1: pre16 = [mu*agg | h | mu]@Wcat + b_self; BN partial sums per rowblock.
// MODE 2: q16 = relu(h16 @ Wh1p + b_h1) (K=256)
// Epilogue: tile -> LDS -> coalesced uint4 global writes (full 64B lines).
// ===========================================================================

template <int MODE, int NCHUNK>
__launch_bounds__(256, 4)
__global__ void gemm_k(const u16* __restrict__ A, const u16* __restrict__ A2,
                       const u16* __restrict__ MU, const u16* __restrict__ Bp,
                       const float* __restrict__ bias, const int* __restrict__ bflag,
                       u16* __restrict__ outH, float* __restrict__ partial,
                       int nrows, int mcols, int astride) {
    __shared__ __align__(16) u16 lds[16384];   // 32KB: [0:8192)=A, [8192:16384)=B; epilogue tile
    __shared__ float bnbuf[512];
    u16* lA = lds;
    u16* lB = lds + 8192;
    const int tid = threadIdx.x;
    const int row0 = blockIdx.x * 128;
    const int c0 = blockIdx.y * 128;
    const int lane = tid & 63;
    const int q = lane >> 4, mm = lane & 15;
    const int wave = tid >> 6;
    const int wm = wave >> 1, wn = wave & 1;

    f32x4 acc[4][4];
#pragma unroll
    for (int i = 0; i < 4; ++i)
#pragma unroll
        for (int j = 0; j < 4; ++j) acc[i][j] = (f32x4){0.f, 0.f, 0.f, 0.f};

    int cb = 0, cbEnd = NCHUNK;
    if (MODE == 1 && bflag[blockIdx.x] == 0) { cb = 64; cbEnd = 68; }  // mu==0: fuzzy+mu K exact-zero

    for (; cb < cbEnd; ++cb) {
#pragma unroll
        for (int it = 0; it < 4; ++it) {
            int idx = it * 256 + tid;
            int p = idx >> 7, col = idx & 127;
            uint4 v = *(const uint4*)(Bp + (((size_t)(cb * 8 + p)) * mcols + c0 + col) * 8);
            *(uint4*)(lB + (size_t)idx * 8) = v;
        }
#pragma unroll
        for (int it = 0; it < 4; ++it) {
            int idx = it * 256 + tid;
            int p = idx >> 7, row = idx & 127;
            int grow = row0 + row; if (grow >= nrows) grow = nrows - 1;
            uint4 v;
            if (MODE != 1) {
                v = *(const uint4*)(A + (size_t)grow * astride + cb * 64 + p * 8);
            } else {
                if (cb < 64) {
                    int r = cb >> 2;
                    int i0 = ((cb & 3) << 6) + (p << 3);
                    v = *(const uint4*)(A + (size_t)grow * 256 + i0);
                    union { u16 u; _Float16 h; } mu; mu.u = MU[(size_t)grow * 16 + r];
                    union { uint4 u4; _Float16 h[8]; } wv; wv.u4 = v;
#pragma unroll
                    for (int j = 0; j < 8; ++j) wv.h[j] = wv.h[j] * mu.h;
                    v = wv.u4;
                } else if (cb < 68) {
                    int i0 = ((cb - 64) << 6) + (p << 3);
                    v = *(const uint4*)(A2 + (size_t)grow * 256 + i0);
                } else {
                    int j0 = p << 3;
                    if (j0 < 16) v = *(const uint4*)(MU + (size_t)grow * 16 + j0);
                    else v = (uint4){0, 0, 0, 0};
                }
            }
            *(uint4*)(lA + (size_t)idx * 8) = v;
        }
        __syncthreads();
#pragma unroll
        for (int kc = 0; kc < 2; ++kc) {
            int pp = kc * 4 + q;
            half8 af[4], bf[4];
#pragma unroll
            for (int mt = 0; mt < 4; ++mt)
                af[mt] = *(const half8*)(lA + ((size_t)pp * 128 + wm * 64 + mt * 16 + mm) * 8);
#pragma unroll
            for (int nt = 0; nt < 4; ++nt)
                bf[nt] = *(const half8*)(lB + ((size_t)pp * 128 + wn * 64 + nt * 16 + mm) * 8);
#pragma unroll
            for (int mt = 0; mt < 4; ++mt)
#pragma unroll
                for (int nt = 0; nt < 4; ++nt)
                    acc[mt][nt] = __builtin_amdgcn_mfma_f32_16x16x32_f16(af[mt], bf[nt], acc[mt][nt], 0, 0, 0);
        }
        __syncthreads();
    }

    // epilogue: C/D layout col=lane&15, row=q*4+reg.  Stage tile in LDS (u16
    // [128][128]) then write coalesced 16B chunks (full 64B lines, no RMW).
#pragma unroll
    for (int nt = 0; nt < 4; ++nt) {
        const int cl = wn * 64 + nt * 16 + mm;
        const int gcol = c0 + cl;
        float s = 0.f, ss = 0.f;
#pragma unroll
        for (int mt = 0; mt < 4; ++mt) {
#pragma unroll
            for (int r = 0; r < 4; ++r) {
                int row = wm * 64 + mt * 16 + q * 4 + r;
                float v = acc[mt][nt][r] + bias[gcol];
                if (MODE != 1) v = fmaxf(v, 0.f);
                union { u16 u; _Float16 h; } cc; cc.h = (_Float16)v;
                lds[row * 128 + cl] = cc.u;
                if (MODE == 1 && row0 + row < nrows) { s += v; ss += v * v; }
            }
        }
        if (MODE == 1) {
            s += __shfl_xor(s, 16);  s += __shfl_xor(s, 32);
            ss += __shfl_xor(ss, 16); ss += __shfl_xor(ss, 32);
            if (q == 0) {
                bnbuf[(wm * 128 + cl) * 2 + 0] = s;
                bnbuf[(wm * 128 + cl) * 2 + 1] = ss;
            }
        }
    }
    __syncthreads();
    {
        int nr = nrows - row0; if (nr > 128) nr = 128;
#pragma unroll
        for (int it = 0; it < 8; ++it) {
            int idx = it * 256 + tid;        // 0..2047 chunks of 16B
            int row = idx >> 4, cp = idx & 15;
            if (row < nr) {
                uint4 v = *(const uint4*)(lds + row * 128 + cp * 8);
                *(uint4*)(outH + (size_t)(row0 + row) * mcols + c0 + cp * 8) = v;
            }
        }
    }
    if (MODE == 1) {
        int cl2 = tid >> 1, comp = tid & 1;
        float v = bnbuf[cl2 * 2 + comp] + bnbuf[(128 + cl2) * 2 + comp];
        partial[(size_t)blockIdx.x * 512 + comp * 256 + c0 + cl2] = v;
    }
}

// ===========================================================================
// bnred_k: bnsum[o] = sum_r partial[r][o], o in [0,512).  grid 2 x 256.
// ===========================================================================

__global__ void bnred_k(const float* __restrict__ partial, float* __restrict__ bnsum, int gx) {
    int o = blockIdx.x * 256 + threadIdx.x;
    float s0 = 0, s1 = 0, s2 = 0, s3 = 0;
    int r = 0;
    for (; r + 4 <= gx; r += 4) {
        s0 += partial[(size_t)r * 512 + o];
        s1 += partial[(size_t)(r + 1) * 512 + o];
        s2 += partial[(size_t)(r + 2) * 512 + o];
        s3 += partial[(size_t)(r + 3) * 512 + o];
    }
    for (; r < gx; ++r) s0 += partial[(size_t)r * 512 + o];
    bnsum[o] = (s0 + s1) + (s2 + s3);
}

// ===========================================================================
// Fused BN-finalize + residual update + (optional) next-layer membership.
// Lane (q,mm) owns node n0+mm, channels {b*32+q*8..+7} — the MFMA A footprint.
// ===========================================================================

template <int DOMEMB>
__launch_bounds__(256)
__global__ void updmemb_k(const u16* __restrict__ pre16, const float* __restrict__ bnsum,
                          const float* __restrict__ gamma, const float* __restrict__ beta,
                          u16* __restrict__ h16,
                          const u16* __restrict__ pcB, const float* __restrict__ pccc,
                          u16* __restrict__ mu16, int* __restrict__ bflag, int n) {
    const int lane = threadIdx.x & 63, wave = threadIdx.x >> 6;
    const int q = lane >> 4, mm = lane & 15;
    const int n0 = (blockIdx.x * 4 + wave) * 16;
    if (n0 >= n) return;
    const int node = n0 + mm;
    const bool valid = node < n;
    const int nodeC = valid ? node : n - 1;
    const float invn = 1.f / (float)n;
    const size_t base = (size_t)nodeC * 256 + q * 8;

    half8 v16[8];
#pragma unroll
    for (int b = 0; b < 8; ++b) {
        int c = b * 32 + q * 8;
        float4 sA = *(const float4*)(bnsum + c);
        float4 sB = *(const float4*)(bnsum + c + 4);
        float4 qA = *(const float4*)(bnsum + 256 + c);
        float4 qB = *(const float4*)(bnsum + 256 + c + 4);
        float4 gA = *(const float4*)(gamma + c);
        float4 gB = *(const float4*)(gamma + c + 4);
        float4 bA = *(const float4*)(beta + c);
        float4 bB = *(const float4*)(beta + c + 4);
        float sarr[8] = {sA.x, sA.y, sA.z, sA.w, sB.x, sB.y, sB.z, sB.w};
        float qarr[8] = {qA.x, qA.y, qA.z, qA.w, qB.x, qB.y, qB.z, qB.w};
        float garr[8] = {gA.x, gA.y, gA.z, gA.w, gB.x, gB.y, gB.z, gB.w};
        float barr[8] = {bA.x, bA.y, bA.z, bA.w, bB.x, bB.y, bB.z, bB.w};
        union { uint4 u; _Float16 hh[8]; } p, hv, o;
        p.u  = *(const uint4*)(pre16 + base + b * 32);
        hv.u = *(const uint4*)(h16 + base + b * 32);
#pragma unroll
        for (int j = 0; j < 8; ++j) {
            float m = sarr[j] * invn;
            float al = garr[j] * rsqrtf(qarr[j] * invn - m * m + 1e-5f);
            float sh = barr[j] - m * al;
            float v = (float)hv.hh[j] + fmaxf((float)p.hh[j] * al + sh, 0.f);
            o.hh[j] = (_Float16)v;
        }
        if (valid) *(uint4*)(h16 + base + b * 32) = o.u;
        v16[b] = *(half8*)&o;
    }

    if (DOMEMB) {
        const u16* brow = pcB + (size_t)mm * 512;
        f32x4 acc = (f32x4){0.f, 0.f, 0.f, 0.f};
#pragma unroll
        for (int it = 0; it < 16; ++it) {
            half8 a = v16[it & 7];
            if (it < 8) a = a * a;
            half8 bb = *(const half8*)(brow + it * 32 + q * 8);
            acc = __builtin_amdgcn_mfma_f32_16x16x32_f16(a, bb, acc, 0, 0, 0);
        }
        float cc = pccc[mm];
        bool any = false;
#pragma unroll
        for (int r = 0; r < 4; ++r) {
            float d = acc[r] + cc;
            float f = expf(-0.5f * d);
            float s = f;
            s += __shfl_xor(s, 1); s += __shfl_xor(s, 2);
            s += __shfl_xor(s, 4); s += __shfl_xor(s, 8);
            int nd = n0 + q * 4 + r;
            if (nd < n) {
                union { u16 u; _Float16 h; } c2;
                c2.h = (_Float16)(f / (s + 1e-12f));
                mu16[(size_t)nd * 16 + mm] = c2.u;
                if (s > 0.f) any = true;
            }
        }
        if (any && mm == 0) {
            atomicOr(&bflag[n0 >> 7], 1);
            atomicOr(&bflag[511], 1);
        }
    }
}

// ===========================================================================
// MFMA head: logits = q16 @ Wh2p + b_h2 (40 cols padded to 48), softmax, f32 out.
// ===========================================================================

__launch_bounds__(256)
__global__ void head2_k(const u16* __restrict__ q16, const u16* __restrict__ wh2p,
                        const float* __restrict__ bh2, float* __restrict__ out, int n) {
    const int lane = threadIdx.x & 63, wave = threadIdx.x >> 6;
    const int q = lane >> 4, mm = lane & 15;
    const int n0 = (blockIdx.x * 4 + wave) * 16;
    if (n0 >= n) return;
    int nodeA = n0 + mm; if (nodeA >= n) nodeA = n - 1;
    const u16* qrow = q16 + (size_t)nodeA * 128;
    f32x4 acc[3];
#pragma unroll
    for (int t = 0; t < 3; ++t) acc[t] = (f32x4){0.f, 0.f, 0.f, 0.f};
#pragma unroll
    for (int c = 0; c < 4; ++c) {
        half8 a = *(const half8*)(qrow + c * 32 + q * 8);
#pragma unroll
        for (int t = 0; t < 3; ++t) {
            half8 b = *(const half8*)(wh2p + ((size_t)(c * 4 + q) * 48 + t * 16 + mm) * 8);
            acc[t] = __builtin_amdgcn_mfma_f32_16x16x32_f16(a, b, acc[t], 0, 0, 0);
        }
    }
    const bool c2ok = (mm < 8);                 // col 32+mm < 40
    float b0 = bh2[mm], b1 = bh2[16 + mm];
    float b2 = c2ok ? bh2[32 + mm] : 0.f;
#pragma unroll
    for (int r = 0; r < 4; ++r) {
        int node = n0 + q * 4 + r;
        float v0 = acc[0][r] + b0;
        float v1 = acc[1][r] + b1;
        float v2 = c2ok ? (acc[2][r] + b2) : -3e38f;
        float m = fmaxf(fmaxf(v0, v1), v2);
        m = fmaxf(m, __shfl_xor(m, 1)); m = fmaxf(m, __shfl_xor(m, 2));
        m = fmaxf(m, __shfl_xor(m, 4)); m = fmaxf(m, __shfl_xor(m, 8));
        float e0 = expf(v0 - m), e1 = expf(v1 - m);
        float e2 = c2ok ? expf(v2 - m) : 0.f;
        float s = e0 + e1 + e2;
        s += __shfl_xor(s, 1); s += __shfl_xor(s, 2);
        s += __shfl_xor(s, 4); s += __shfl_xor(s, 8);
        float is = 1.f / s;
        if (node < n) {
            float* op = out + (size_t)node * 40;
            op[mm] = e0 * is;
            op[16 + mm] = e1 * is;
            if (c2ok) op[32 + mm] = e2 * is;
        }
    }
}

// ===========================================================================
// Launch
// ===========================================================================

extern "C" void kernel_launch(void* const* d_in, const int* in_sizes, int n_in,
                              void* d_out, int out_size, void* d_ws, size_t ws_size,
                              hipStream_t stream) {
    const float* x       = (const float*)d_in[0];
    const int*   ei      = (const int*)d_in[1];
    const float* W_in    = (const float*)d_in[2];
    const float* b_in    = (const float*)d_in[3];
    const float* centers = (const float*)d_in[4];
    const float* logsig  = (const float*)d_in[5];
    const float* W_rule  = (const float*)d_in[6];
    const float* b_rule  = (const float*)d_in[7];
    const float* W_self  = (const float*)d_in[8];
    const float* b_self  = (const float*)d_in[9];
    const float* gamma   = (const float*)d_in[10];
    const float* beta    = (const float*)d_in[11];
    const float* W_h1    = (const float*)d_in[12];
    const float* b_h1    = (const float*)d_in[13];
    const float* W_h2    = (const float*)d_in[14];
    const float* b_h2    = (const float*)d_in[15];

    const int N = in_sizes[0] / 128;
    const int E = in_sizes[1] / 2;
    const int* e_src = ei;
    const int* e_dst = ei + E;

    char* w = (char*)d_ws;
    size_t off = 0;
    auto alloc = [&](size_t bytes) -> void* {
        void* p = w + off;
        off = (off + bytes + 255) & ~(size_t)255;
        return p;
    };

    const int gx = cdiv(N, 128);

    u16*   x16    = (u16*)  alloc((size_t)N * 128 * 2);
    u16*   h16    = (u16*)  alloc((size_t)N * 256 * 2);
    u16*   pre16  = (u16*)  alloc((size_t)N * 256 * 2);
    u16*   agg16  = (u16*)  alloc((size_t)N * 256 * 2);
    u16*   mu16   = (u16*)  alloc((size_t)N * 16 * 2);
    u16*   q16    = (u16*)  alloc((size_t)N * 128 * 2);
    u16*   wcat   = (u16*)  alloc((size_t)3 * 552 * 256 * 8 * 2);
    u16*   winp   = (u16*)  alloc((size_t)16 * 256 * 8 * 2);
    u16*   wh1p   = (u16*)  alloc((size_t)32 * 128 * 8 * 2);
    u16*   wh2p   = (u16*)  alloc((size_t)16 * 48 * 8 * 2);
    u16*   pcB    = (u16*)  alloc((size_t)48 * 512 * 2);
    float* pccc   = (float*)alloc((size_t)48 * 4);
    int*   indptr = (int*)  alloc((size_t)(N + 1) * 4);
    int*   cursor = (int*)  alloc((size_t)N * 4);
    float* deginv = (float*)alloc((size_t)N * 4);
    int*   ssrc   = (int*)  alloc((size_t)E * 4);
    float* partial= (float*)alloc((size_t)gx * 512 * 4);
    float* bnsumA = (float*)alloc((size_t)3 * 512 * 4);
    // zero region: [deg N][bflag 3*512][csr_done pad]
    const int nzero = N + 3 * 512 + 64;
    int*   zerob  = (int*)  alloc((size_t)nzero * 4);
    int*   deg    = zerob;
    int*   bflagA = zerob + N;
    int*   done   = zerob + N + 3 * 512;

    const int Z = cdiv(nzero, 256);
    const int C = cdiv(N * 32, 256);
    const int Wb = 3 * 552 * 256 * 8 / 256;   // 13248
    const int prep_grid = Z + C + Wb + 128 + 128 + 24 + 48;

    prep_k<<<prep_grid, 256, 0, stream>>>(x, W_rule, W_self, b_rule, W_in, W_h1, W_h2,
                                          centers, logsig, x16, wcat, winp, wh1p, wh2p,
                                          pcB, pccc, zerob, nzero, Z, C, Wb, N);

    gemm_k<0, 2><<<dim3(gx, 2), 256, 0, stream>>>(x16, nullptr, nullptr, winp, b_in,
                                                  nullptr, h16, nullptr, N, 256, 128);
    memb_k<<<cdiv(N, 64), 256, 0, stream>>>(h16, pcB, pccc, mu16, bflagA, N);

    for (int l = 0; l < 3; ++l) {
        int* bf = bflagA + l * 512;
        int* bany = bf + 511;
        float* bns = bnsumA + l * 512;
        deg_count_g<<<1024, 256, 0, stream>>>(e_dst, deg, bany, done, E);
        csr_scan_g<<<1, 1024, 0, stream>>>(deg, indptr, cursor, deginv, bany, done, N);
        edge_scatter_g<<<1024, 256, 0, stream>>>(e_src, e_dst, cursor, ssrc, bany, done, E);
        agg_k<<<1024, 256, 0, stream>>>(h16, indptr, ssrc, deginv, bf, done, agg16, N);
        gemm_k<1, 69><<<dim3(gx, 2), 256, 0, stream>>>(agg16, h16, mu16,
                                                       wcat + (size_t)l * 552 * 256 * 8,
                                                       b_self + l * 256, bf, pre16,
                                                       partial, N, 256, 0);
        bnred_k<<<2, 256, 0, stream>>>(partial, bns, gx);
        if (l < 2) {
            updmemb_k<1><<<cdiv(N, 64), 256, 0, stream>>>(pre16, bns, gamma + l * 256,
                                                          beta + l * 256, h16,
                                                          pcB + (size_t)(l + 1) * 16 * 512,
                                                          pccc + (l + 1) * 16, mu16,
                                                          bflagA + (l + 1) * 512, N);
        } else {
            updmemb_k<0><<<cdiv(N, 64), 256, 0, stream>>>(pre16, bns, gamma + l * 256,
                                                          beta + l * 256, h16,
                                                          nullptr, nullptr, nullptr,
                                                          nullptr, N);
        }
    }

    gemm_k<2, 4><<<dim3(gx, 1), 256, 0, stream>>>(h16, nullptr, nullptr, wh1p, b_h1,
                                                  nullptr, q16, nullptr, N, 128, 256);
    head2_k<<<cdiv(N, 64), 256, 0, stream>>>(q16, wh2p, b_h2, (float*)d_out, N);
}

// Round 9
// 352.773 us; speedup vs baseline: 1.4725x; 1.1890x over previous
//
#include <hip/hip_runtime.h>
#include <hip/hip_fp16.h>
#include <cstdint>
#include <cstddef>

using u16 = unsigned short;
using u32 = unsigned int;

typedef _Float16 half8 __attribute__((ext_vector_type(8)));
typedef float f32x4 __attribute__((ext_vector_type(4)));

static inline int cdiv(int a, int b) { return (a + b - 1) / b; }

// ===========================================================================
// prep_k: fused zero-init + f16 cast + weight panelization + rule precompute.
// ===========================================================================

__global__ void prep_k(const float* __restrict__ x, const float* __restrict__ Wr,
                       const float* __restrict__ Ws, const float* __restrict__ br,
                       const float* __restrict__ W_in, const float* __restrict__ W_h1,
                       const float* __restrict__ W_h2,
                       const float* __restrict__ centers, const float* __restrict__ logsig,
                       u16* __restrict__ x16, u16* __restrict__ wcat,
                       u16* __restrict__ winp, u16* __restrict__ wh1p,
                       u16* __restrict__ wh2p,
                       u16* __restrict__ pcB, float* __restrict__ pccc,
                       int* __restrict__ zerobase, int nzero,
                       int Z, int C, int Wb, int N) {
    const int bid = blockIdx.x;
    const int tid = threadIdx.x;
    if (bid < Z) {                                   // zero-init region
        int i = bid * 256 + tid;
        if (i < nzero) zerobase[i] = 0;
        return;
    }
    if (bid < Z + C) {                               // x -> f16
        size_t i = (size_t)(bid - Z) * 256 + tid;
        if (i >= (size_t)N * 32) return;
        float4 v = *(const float4*)(x + i * 4);
        union { uint2 u; _Float16 h[4]; } o;
        o.h[0] = (_Float16)v.x; o.h[1] = (_Float16)v.y;
        o.h[2] = (_Float16)v.z; o.h[3] = (_Float16)v.w;
        *(uint2*)(x16 + i * 4) = o.u;
        return;
    }
    if (bid < Z + C + Wb) {                          // wcat panels [552][256][8] x3 layers
        size_t t = (size_t)(bid - Z - C) * 256 + tid;
        const size_t PL = 552u * 256u * 8u;
        int l = (int)(t / PL);
        size_t rem = t - (size_t)l * PL;
        int kp = (int)(rem >> 11);
        int o = (int)((rem >> 3) & 255);
        int e = (int)(rem & 7);
        int k = kp * 8 + e;
        float v;
        if (k < 4096)      v = Wr[((((size_t)l * 16 + (k >> 8)) * 256) + (k & 255)) * 256 + o];
        else if (k < 4352) v = Ws[(((size_t)l * 256) + (k - 4096)) * 256 + o];
        else if (k < 4368) v = br[(((size_t)l * 16) + (k - 4352)) * 256 + o];
        else               v = 0.f;
        union { u16 u; _Float16 h; } c; c.h = (_Float16)v;
        wcat[t] = c.u;
        return;
    }
    if (bid < Z + C + Wb + 128) {                    // panelize W_in (K=128,M=256)
        size_t t = (size_t)(bid - Z - C - Wb) * 256 + tid;
        int e = (int)(t & 7), o = (int)((t >> 3) & 255);
        int kp = (int)(t >> 11);
        union { u16 u; _Float16 h; } c; c.h = (_Float16)W_in[(size_t)(kp * 8 + e) * 256 + o];
        winp[t] = c.u;
        return;
    }
    if (bid < Z + C + Wb + 256) {                    // panelize W_h1 (K=256,M=128)
        size_t t = (size_t)(bid - Z - C - Wb - 128) * 256 + tid;
        int e = (int)(t & 7), o = (int)((t >> 3) & 127);
        int kp = (int)(t >> 10);
        union { u16 u; _Float16 h; } c; c.h = (_Float16)W_h1[(size_t)(kp * 8 + e) * 128 + o];
        wh1p[t] = c.u;
        return;
    }
    if (bid < Z + C + Wb + 256 + 24) {               // panelize W_h2 (K=128,M=40->48 pad)
        int t = (bid - Z - C - Wb - 256) * 256 + tid; // 16*48*8 = 6144
        int e = t & 7, col = (t >> 3) % 48, p = t / 384;
        int k = p * 8 + e;
        float v = (col < 40) ? W_h2[(size_t)k * 40 + col] : 0.f;
        union { u16 u; _Float16 h; } c; c.h = (_Float16)v;
        wh2p[t] = c.u;
        return;
    }
    {                                                // pc_build: 48 blocks (l*16+r)
        int lr = bid - (Z + C + Wb + 256 + 24);
        size_t idx = (size_t)lr * 256 + tid;
        float ls = logsig[idx];
        float inv = expf(-2.f * ls);
        float c = centers[idx];
        union { u16 u; _Float16 h; } c1, c2;
        c1.h = (_Float16)inv;
        c2.h = (_Float16)(-2.f * c * inv);
        pcB[(size_t)lr * 512 + tid] = c1.u;          // B[k][r] = inv_s2[r][k], k<256
        pcB[(size_t)lr * 512 + 256 + tid] = c2.u;    // B[256+k][r] = -2 c inv
        __shared__ float sm[256];
        sm[tid] = c * c * inv;
        __syncthreads();
        for (int s = 128; s > 0; s >>= 1) { if (tid < s) sm[tid] += sm[tid + s]; __syncthreads(); }
        if (tid == 0) pccc[lr] = sm[0];
    }
}

// ===========================================================================
// Gated CSR build (cold path only; in this data the gate never fires).
// deg_scan_g: count degrees, last-done block runs the serial scan.
// ===========================================================================

__global__ void deg_scan_g(const int* __restrict__ dst, int* __restrict__ deg,
                           int* __restrict__ indptr, int* __restrict__ cursor,
                           float* __restrict__ deginv, int* __restrict__ ctr,
                           const int* __restrict__ bany, const int* __restrict__ done,
                           int E, int n, int nblocks) {
    if (*bany == 0 || *done != 0) return;
    for (int e = blockIdx.x * 256 + threadIdx.x; e < E; e += gridDim.x * 256)
        atomicAdd(&deg[dst[e]], 1);
    __threadfence();
    __shared__ int lastf;
    if (threadIdx.x == 0) lastf = (atomicAdd(ctr, 1) == nblocks - 1);
    __syncthreads();
    if (!lastf) return;
    // 256-thread exclusive scan over deg[0..n)
    const int tid = threadIdx.x;
    const int chunk = (n + 255) >> 8;
    int s0 = tid * chunk, s1 = s0 + chunk; if (s1 > n) s1 = n; if (s0 > n) s0 = n;
    int tot = 0;
    for (int i = s0; i < s1; ++i) tot += atomicAdd(&deg[i], 0);   // coherent read
    __shared__ int sm[256];
    sm[tid] = tot; __syncthreads();
    for (int off = 1; off < 256; off <<= 1) {
        int t = (tid >= off) ? sm[tid - off] : 0;
        __syncthreads(); sm[tid] += t; __syncthreads();
    }
    int base = sm[tid] - tot;
    for (int i = s0; i < s1; ++i) {
        int d = atomicAdd(&deg[i], 0);
        indptr[i] = base; cursor[i] = base;
        deginv[i] = 1.f / (float)(d > 1 ? d : 1);
        base += d;
    }
    if (tid == 255) indptr[n] = sm[255];
}

__global__ void edge_scatter_g(const int* __restrict__ src, const int* __restrict__ dst,
                               int* __restrict__ cursor, int* __restrict__ ssrc,
                               const int* __restrict__ bany, const int* __restrict__ done, int E) {
    if (*bany == 0 || *done != 0) return;
    for (int e = blockIdx.x * 256 + threadIdx.x; e < E; e += gridDim.x * 256) {
        int d = dst[e];
        int pos = atomicAdd(&cursor[d], 1);
        ssrc[pos] = src[e];
    }
}

// ===========================================================================
// MFMA membership (standalone, layer 0): d = [h^2|h] @ pcB + cc; mu = norm.
// ===========================================================================

__launch_bounds__(256)
__global__ void memb_k(const u16* __restrict__ h16, const u16* __restrict__ pcB,
                       const float* __restrict__ pccc,
                       u16* __restrict__ mu16, int* __restrict__ bflag, int n) {
    const int lane = threadIdx.x & 63, wave = threadIdx.x >> 6;
    const int q = lane >> 4, mm = lane & 15;
    const int n0 = (blockIdx.x * 4 + wave) * 16;
    if (n0 >= n) return;
    int nodeA = n0 + mm; if (nodeA >= n) nodeA = n - 1;
    const u16* hrow = h16 + (size_t)nodeA * 256;
    const u16* brow = pcB + (size_t)mm * 512;
    f32x4 acc = (f32x4){0.f, 0.f, 0.f, 0.f};
#pragma unroll
    for (int it = 0; it < 16; ++it) {
        int k = it * 32 + q * 8;
        half8 b = *(const half8*)(brow + k);
        half8 a;
        if (k < 256) {
            a = *(const half8*)(hrow + k);
            a = a * a;
        } else {
            a = *(const half8*)(hrow + (k - 256));
        }
        acc = __builtin_amdgcn_mfma_f32_16x16x32_f16(a, b, acc, 0, 0, 0);
    }
    float cc = pccc[mm];
    bool any = false;
#pragma unroll
    for (int r = 0; r < 4; ++r) {
        float d = acc[r] + cc;
        float f = expf(-0.5f * d);
        float s = f;
        s += __shfl_xor(s, 1); s += __shfl_xor(s, 2);
        s += __shfl_xor(s, 4); s += __shfl_xor(s, 8);
        int node = n0 + q * 4 + r;
        if (node < n) {
            union { u16 u; _Float16 h; } c2;
            c2.h = (_Float16)(f / (s + 1e-12f));
            mu16[(size_t)node * 16 + mm] = c2.u;
            if (s > 0.f) any = true;
        }
    }
    if (any && mm == 0) {
        atomicOr(&bflag[n0 >> 7], 1);
        atomicOr(&bflag[511], 1);
    }
}

// ===========================================================================
// Neighbor mean (grid-stride; early-exits unless this layer fired).
// ===========================================================================

__global__ void agg_k(const u16* __restrict__ h16, const int* __restrict__ indptr,
                      const int* __restrict__ ssrc, const float* __restrict__ deginv,
                      const int* __restrict__ bflag, int* __restrict__ done,
                      u16* __restrict__ agg16, int n) {
    if (bflag[511] == 0) return;
    if (blockIdx.x == 0 && threadIdx.x == 0 && *done == 0) *done = 1;
    int lane = threadIdx.x & 63, wave = threadIdx.x >> 6;
    for (int node = blockIdx.x * 4 + wave; node < n; node += gridDim.x * 4) {
        if (bflag[node >> 7] == 0) continue;
        int j0 = indptr[node], j1 = indptr[node + 1];
        float a0 = 0, a1 = 0, a2 = 0, a3 = 0;
        for (int j = j0; j < j1; ++j) {
            int sN = ssrc[j];
            union { uint2 u; _Float16 h[4]; } hv;
            hv.u = *(const uint2*)(h16 + (size_t)sN * 256 + lane * 4);
            a0 += (float)hv.h[0]; a1 += (float)hv.h[1];
            a2 += (float)hv.h[2]; a3 += (float)hv.h[3];
        }
        float di = deginv[node];
        union { uint2 u; _Float16 h[4]; } o;
        o.h[0] = (_Float16)(a0 * di); o.h[1] = (_Float16)(a1 * di);
        o.h[2] = (_Float16)(a2 * di); o.h[3] = (_Float16)(a3 * di);
        *(uint2*)(agg16 + (size_t)node * 256 + lane * 4) = o.u;
    }
}

// ===========================================================================
// Unified f16 MFMA GEMM. 128x128 tile, BK=64, 256 threads (4 waves).
// MODE 0: h16 = relu(x16 @ Winp + b_in)   (K=128)
// MODE 1: pre16 = [mu*agg | h | mu]@Wcat + b_self; BN partial sums per rowblock.
// MODE 2: relu(h16 @ Wh1p + b_h1) kept in LDS, then fused head GEMM + softmax
//         -> outF (f32 probs). No intermediate global write.
// Epilogue (0/1): tile -> LDS (stride 136) -> coalesced uint4 global writes.
// ===========================================================================

template <int MODE, int NCHUNK>
__launch_bounds__(256, 4)
__global__ void gemm_k(const u16* __restrict__ A, const u16* __restrict__ A2,
                       const u16* __restrict__ MU, const u16* __restrict__ Bp,
                       const float* __restrict__ bias, const int* __restrict__ bflag,
                       u16* __restrict__ outH, float* __restrict__ partial,
                       const u16* __restrict__ wh2, const float* __restrict__ bh2,
                       float* __restrict__ outF,
                       int nrows, int mcols, int astride) {
    __shared__ __align__(16) u16 lds[17408];   // staging (16K u16) / out tile 128x136
    __shared__ float bnbuf[512];
    u16* lA = lds;
    u16* lB = lds + 8192;
    const int tid = threadIdx.x;
    const int row0 = blockIdx.x * 128;
    const int c0 = blockIdx.y * 128;
    const int lane = tid & 63;
    const int q = lane >> 4, mm = lane & 15;
    const int wave = tid >> 6;
    const int wm = wave >> 1, wn = wave & 1;

    f32x4 acc[4][4];
#pragma unroll
    for (int i = 0; i < 4; ++i)
#pragma unroll
        for (int j = 0; j < 4; ++j) acc[i][j] = (f32x4){0.f, 0.f, 0.f, 0.f};

    int cb = 0, cbEnd = NCHUNK;
    if (MODE == 1 && bflag[blockIdx.x] == 0) { cb = 64; cbEnd = 68; }  // mu==0: fuzzy+mu K exact-zero

    for (; cb < cbEnd; ++cb) {
#pragma unroll
        for (int it = 0; it < 4; ++it) {
            int idx = it * 256 + tid;
            int p = idx >> 7, col = idx & 127;
            uint4 v = *(const uint4*)(Bp + (((size_t)(cb * 8 + p)) * mcols + c0 + col) * 8);
            *(uint4*)(lB + (size_t)idx * 8) = v;
        }
#pragma unroll
        for (int it = 0; it < 4; ++it) {
            int idx = it * 256 + tid;
            int p = idx >> 7, row = idx & 127;
            int grow = row0 + row; if (grow >= nrows) grow = nrows - 1;
            uint4 v;
            if (MODE != 1) {
                v = *(const uint4*)(A + (size_t)grow * astride + cb * 64 + p * 8);
            } else {
                if (cb < 64) {
                    int r = cb >> 2;
                    int i0 = ((cb & 3) << 6) + (p << 3);
                    v = *(const uint4*)(A + (size_t)grow * 256 + i0);
                    union { u16 u; _Float16 h; } mu; mu.u = MU[(size_t)grow * 16 + r];
                    union { uint4 u4; _Float16 h[8]; } wv; wv.u4 = v;
#pragma unroll
                    for (int j = 0; j < 8; ++j) wv.h[j] = wv.h[j] * mu.h;
                    v = wv.u4;
                } else if (cb < 68) {
                    int i0 = ((cb - 64) << 6) + (p << 3);
                    v = *(const uint4*)(A2 + (size_t)grow * 256 + i0);
                } else {
                    int j0 = p << 3;
                    if (j0 < 16) v = *(const uint4*)(MU + (size_t)grow * 16 + j0);
                    else v = (uint4){0, 0, 0, 0};
                }
            }
            *(uint4*)(lA + (size_t)idx * 8) = v;
        }
        __syncthreads();
#pragma unroll
        for (int kc = 0; kc < 2; ++kc) {
            int pp = kc * 4 + q;
            half8 af[4], bf[4];
#pragma unroll
            for (int mt = 0; mt < 4; ++mt)
                af[mt] = *(const half8*)(lA + ((size_t)pp * 128 + wm * 64 + mt * 16 + mm) * 8);
#pragma unroll
            for (int nt = 0; nt < 4; ++nt)
                bf[nt] = *(const half8*)(lB + ((size_t)pp * 128 + wn * 64 + nt * 16 + mm) * 8);
#pragma unroll
            for (int mt = 0; mt < 4; ++mt)
#pragma unroll
                for (int nt = 0; nt < 4; ++nt)
                    acc[mt][nt] = __builtin_amdgcn_mfma_f32_16x16x32_f16(af[mt], bf[nt], acc[mt][nt], 0, 0, 0);
        }
        __syncthreads();
    }

    // epilogue: C/D layout col=lane&15, row=q*4+reg.  Stage tile in LDS
    // (u16 [128][136], padded) for coalesced writes / fused head.
#pragma unroll
    for (int nt = 0; nt < 4; ++nt) {
        const int cl = wn * 64 + nt * 16 + mm;
        const int gcol = c0 + cl;
        float s = 0.f, ss = 0.f;
#pragma unroll
        for (int mt = 0; mt < 4; ++mt) {
#pragma unroll
            for (int r = 0; r < 4; ++r) {
                int row = wm * 64 + mt * 16 + q * 4 + r;
                float v = acc[mt][nt][r] + bias[gcol];
                if (MODE != 1) v = fmaxf(v, 0.f);
                union { u16 u; _Float16 h; } cc; cc.h = (_Float16)v;
                lds[row * 136 + cl] = cc.u;
                if (MODE == 1 && row0 + row < nrows) { s += v; ss += v * v; }
            }
        }
        if (MODE == 1) {
            s += __shfl_xor(s, 16);  s += __shfl_xor(s, 32);
            ss += __shfl_xor(ss, 16); ss += __shfl_xor(ss, 32);
            if (q == 0) {
                bnbuf[(wm * 128 + cl) * 2 + 0] = s;
                bnbuf[(wm * 128 + cl) * 2 + 1] = ss;
            }
        }
    }
    __syncthreads();

    if (MODE != 2) {
        int nr = nrows - row0; if (nr > 128) nr = 128;
#pragma unroll
        for (int it = 0; it < 8; ++it) {
            int idx = it * 256 + tid;        // 0..2047 chunks of 16B
            int row = idx >> 4, cp = idx & 15;
            if (row < nr) {
                uint4 v = *(const uint4*)(lds + row * 136 + cp * 8);
                *(uint4*)(outH + (size_t)(row0 + row) * mcols + c0 + cp * 8) = v;
            }
        }
        if (MODE == 1) {
            int cl2 = tid >> 1, comp = tid & 1;
            float v = bnbuf[cl2 * 2 + comp] + bnbuf[(128 + cl2) * 2 + comp];
            partial[(size_t)blockIdx.x * 512 + comp * 256 + c0 + cl2] = v;
        }
    } else {
        // fused head: q-tile (128x128, stride 136) @ wh2 (48-padded) + softmax
        const bool c2ok = (mm < 8);
        float b0 = bh2[mm], b1 = bh2[16 + mm];
        float b2 = c2ok ? bh2[32 + mm] : 0.f;
#pragma unroll
        for (int half = 0; half < 2; ++half) {
            int rbase = half * 64 + wave * 16;    // 16-node group
            f32x4 hacc[3];
#pragma unroll
            for (int t = 0; t < 3; ++t) hacc[t] = (f32x4){0.f, 0.f, 0.f, 0.f};
#pragma unroll
            for (int c = 0; c < 4; ++c) {
                half8 a = *(const half8*)(lds + (rbase + mm) * 136 + c * 32 + q * 8);
#pragma unroll
                for (int t = 0; t < 3; ++t) {
                    half8 b = *(const half8*)(wh2 + ((size_t)(c * 4 + q) * 48 + t * 16 + mm) * 8);
                    hacc[t] = __builtin_amdgcn_mfma_f32_16x16x32_f16(a, b, hacc[t], 0, 0, 0);
                }
            }
#pragma unroll
            for (int r = 0; r < 4; ++r) {
                int node = row0 + rbase + q * 4 + r;
                float v0 = hacc[0][r] + b0;
                float v1 = hacc[1][r] + b1;
                float v2 = c2ok ? (hacc[2][r] + b2) : -3e38f;
                float m = fmaxf(fmaxf(v0, v1), v2);
                m = fmaxf(m, __shfl_xor(m, 1)); m = fmaxf(m, __shfl_xor(m, 2));
                m = fmaxf(m, __shfl_xor(m, 4)); m = fmaxf(m, __shfl_xor(m, 8));
                float e0 = expf(v0 - m), e1 = expf(v1 - m);
                float e2 = c2ok ? expf(v2 - m) : 0.f;
                float s = e0 + e1 + e2;
                s += __shfl_xor(s, 1); s += __shfl_xor(s, 2);
                s += __shfl_xor(s, 4); s += __shfl_xor(s, 8);
                float is = 1.f / s;
                if (node < nrows) {
                    float* op = outF + (size_t)node * 40;
                    op[mm] = e0 * is;
                    op[16 + mm] = e1 * is;
                    if (c2ok) op[32 + mm] = e2 * is;
                }
            }
        }
    }
}

// ===========================================================================
// bnred_k: bnsum[o] += partial rows (32 blocks, 16-deep f32 atomics).
// ===========================================================================

__global__ void bnred_k(const float* __restrict__ partial, float* __restrict__ bnsum, int gx) {
    int o = (blockIdx.x & 1) * 256 + threadIdx.x;
    int g = blockIdx.x >> 1;
    float s = 0.f;
    for (int r = g; r < gx; r += 16) s += partial[(size_t)r * 512 + o];
    atomicAdd(&bnsum[o], s);
}

// ===========================================================================
// Fused BN-finalize + residual update + (optional) next-layer membership.
// ===========================================================================

template <int DOMEMB>
__launch_bounds__(256)
__global__ void updmemb_k(const u16* __restrict__ pre16, const float* __restrict__ bnsum,
                          const float* __restrict__ gamma, const float* __restrict__ beta,
                          u16* __restrict__ h16,
                          const u16* __restrict__ pcB, const float* __restrict__ pccc,
                          u16* __restrict__ mu16, int* __restrict__ bflag, int n) {
    const int lane = threadIdx.x & 63, wave = threadIdx.x >> 6;
    const int q = lane >> 4, mm = lane & 15;
    const int n0 = (blockIdx.x * 4 + wave) * 16;
    if (n0 >= n) return;
    const int node = n0 + mm;
    const bool valid = node < n;
    const int nodeC = valid ? node : n - 1;
    const float invn = 1.f / (float)n;
    const size_t base = (size_t)nodeC * 256 + q * 8;

    half8 v16[8];
#pragma unroll
    for (int b = 0; b < 8; ++b) {
        int c = b * 32 + q * 8;
        float4 sA = *(const float4*)(bnsum + c);
        float4 sB = *(const float4*)(bnsum + c + 4);
        float4 qA = *(const float4*)(bnsum + 256 + c);
        float4 qB = *(const float4*)(bnsum + 256 + c + 4);
        float4 gA = *(const float4*)(gamma + c);
        float4 gB = *(const float4*)(gamma + c + 4);
        float4 bA = *(const float4*)(beta + c);
        float4 bB = *(const float4*)(beta + c + 4);
        float sarr[8] = {sA.x, sA.y, sA.z, sA.w, sB.x, sB.y, sB.z, sB.w};
        float qarr[8] = {qA.x, qA.y, qA.z, qA.w, qB.x, qB.y, qB.z, qB.w};
        float garr[8] = {gA.x, gA.y, gA.z, gA.w, gB.x, gB.y, gB.z, gB.w};
        float barr[8] = {bA.x, bA.y, bA.z, bA.w, bB.x, bB.y, bB.z, bB.w};
        union { uint4 u; _Float16 hh[8]; } p, hv, o;
        p.u  = *(const uint4*)(pre16 + base + b * 32);
        hv.u = *(const uint4*)(h16 + base + b * 32);
#pragma unroll
        for (int j = 0; j < 8; ++j) {
            float m = sarr[j] * invn;
            float al = garr[j] * rsqrtf(qarr[j] * invn - m * m + 1e-5f);
            float sh = barr[j] - m * al;
            float v = (float)hv.hh[j] + fmaxf((float)p.hh[j] * al + sh, 0.f);
            o.hh[j] = (_Float16)v;
        }
        if (valid) *(uint4*)(h16 + base + b * 32) = o.u;
        v16[b] = *(half8*)&o;
    }

    if (DOMEMB) {
        const u16* brow = pcB + (size_t)mm * 512;
        f32x4 acc = (f32x4){0.f, 0.f, 0.f, 0.f};
#pragma unroll
        for (int it = 0; it < 16; ++it) {
            half8 a = v16[it & 7];
            if (it < 8) a = a * a;
            half8 bb = *(const half8*)(brow + it * 32 + q * 8);
            acc = __builtin_amdgcn_mfma_f32_16x16x32_f16(a, bb, acc, 0, 0, 0);
        }
        float cc = pccc[mm];
        bool any = false;
#pragma unroll
        for (int r = 0; r < 4; ++r) {
            float d = acc[r] + cc;
            float f = expf(-0.5f * d);
            float s = f;
            s += __shfl_xor(s, 1); s += __shfl_xor(s, 2);
            s += __shfl_xor(s, 4); s += __shfl_xor(s, 8);
            int nd = n0 + q * 4 + r;
            if (nd < n) {
                union { u16 u; _Float16 h; } c2;
                c2.h = (_Float16)(f / (s + 1e-12f));
                mu16[(size_t)nd * 16 + mm] = c2.u;
                if (s > 0.f) any = true;
            }
        }
        if (any && mm == 0) {
            atomicOr(&bflag[n0 >> 7], 1);
            atomicOr(&bflag[511], 1);
        }
    }
}

// ===========================================================================
// Launch
// ===========================================================================

extern "C" void kernel_launch(void* const* d_in, const int* in_sizes, int n_in,
                              void* d_out, int out_size, void* d_ws, size_t ws_size,
                              hipStream_t stream) {
    const float* x       = (const float*)d_in[0];
    const int*   ei      = (const int*)d_in[1];
    const float* W_in    = (const float*)d_in[2];
    const float* b_in    = (const float*)d_in[3];
    const float* centers = (const float*)d_in[4];
    const float* logsig  = (const float*)d_in[5];
    const float* W_rule  = (const float*)d_in[6];
    const float* b_rule  = (const float*)d_in[7];
    const float* W_self  = (const float*)d_in[8];
    const float* b_self  = (const float*)d_in[9];
    const float* gamma   = (const float*)d_in[10];
    const float* beta    = (const float*)d_in[11];
    const float* W_h1    = (const float*)d_in[12];
    const float* b_h1    = (const float*)d_in[13];
    const float* W_h2    = (const float*)d_in[14];
    const float* b_h2    = (const float*)d_in[15];

    const int N = in_sizes[0] / 128;
    const int E = in_sizes[1] / 2;
    const int* e_src = ei;
    const int* e_dst = ei + E;

    char* w = (char*)d_ws;
    size_t off = 0;
    auto alloc = [&](size_t bytes) -> void* {
        void* p = w + off;
        off = (off + bytes + 255) & ~(size_t)255;
        return p;
    };

    const int gx = cdiv(N, 128);

    u16*   x16    = (u16*)  alloc((size_t)N * 128 * 2);
    u16*   h16    = (u16*)  alloc((size_t)N * 256 * 2);
    u16*   pre16  = (u16*)  alloc((size_t)N * 256 * 2);
    u16*   agg16  = (u16*)  alloc((size_t)N * 256 * 2);
    u16*   mu16   = (u16*)  alloc((size_t)N * 16 * 2);
    u16*   wcat   = (u16*)  alloc((size_t)3 * 552 * 256 * 8 * 2);
    u16*   winp   = (u16*)  alloc((size_t)16 * 256 * 8 * 2);
    u16*   wh1p   = (u16*)  alloc((size_t)32 * 128 * 8 * 2);
    u16*   wh2p   = (u16*)  alloc((size_t)16 * 48 * 8 * 2);
    u16*   pcB    = (u16*)  alloc((size_t)48 * 512 * 2);
    float* pccc   = (float*)alloc((size_t)48 * 4);
    int*   indptr = (int*)  alloc((size_t)(N + 1) * 4);
    int*   cursor = (int*)  alloc((size_t)N * 4);
    float* deginv = (float*)alloc((size_t)N * 4);
    int*   ssrc   = (int*)  alloc((size_t)E * 4);
    float* partial= (float*)alloc((size_t)gx * 512 * 4);
    // zero region: [deg N][bflag 3*512][bnsum 3*512][done, ctr pad]
    const int nzero = N + 3 * 512 + 3 * 512 + 64;
    int*   zerob  = (int*)  alloc((size_t)nzero * 4);
    int*   deg    = zerob;
    int*   bflagA = zerob + N;
    float* bnsumA = (float*)(zerob + N + 3 * 512);
    int*   done   = zerob + N + 3 * 512 + 3 * 512;
    int*   ctr    = done + 1;

    const int Z = cdiv(nzero, 256);
    const int C = cdiv(N * 32, 256);
    const int Wb = 3 * 552 * 256 * 8 / 256;   // 13248
    const int prep_grid = Z + C + Wb + 128 + 128 + 24 + 48;

    prep_k<<<prep_grid, 256, 0, stream>>>(x, W_rule, W_self, b_rule, W_in, W_h1, W_h2,
                                          centers, logsig, x16, wcat, winp, wh1p, wh2p,
                                          pcB, pccc, zerob, nzero, Z, C, Wb, N);

    gemm_k<0, 2><<<dim3(gx, 2), 256, 0, stream>>>(x16, nullptr, nullptr, winp, b_in,
                                                  nullptr, h16, nullptr, nullptr, nullptr,
                                                  nullptr, N, 256, 128);
    memb_k<<<cdiv(N, 64), 256, 0, stream>>>(h16, pcB, pccc, mu16, bflagA, N);

    for (int l = 0; l < 3; ++l) {
        int* bf = bflagA + l * 512;
        int* bany = bf + 511;
        float* bns = bnsumA + l * 512;
        deg_scan_g<<<256, 256, 0, stream>>>(e_dst, deg, indptr, cursor, deginv, ctr,
                                            bany, done, E, N, 256);
        edge_scatter_g<<<512, 256, 0, stream>>>(e_src, e_dst, cursor, ssrc, bany, done, E);
        agg_k<<<416, 256, 0, stream>>>(h16, indptr, ssrc, deginv, bf, done, agg16, N);
        gemm_k<1, 69><<<dim3(gx, 2), 256, 0, stream>>>(agg16, h16, mu16,
                                                       wcat + (size_t)l * 552 * 256 * 8,
                                                       b_self + l * 256, bf, pre16,
                                                       partial, nullptr, nullptr, nullptr,
                                                       N, 256, 0);
        bnred_k<<<32, 256, 0, stream>>>(partial, bns, gx);
        if (l < 2) {
            updmemb_k<1><<<cdiv(N, 64), 256, 0, stream>>>(pre16, bns, gamma + l * 256,
                                                          beta + l * 256, h16,
                                                          pcB + (size_t)(l + 1) * 16 * 512,
                                                          pccc + (l + 1) * 16, mu16,
                                                          bflagA + (l + 1) * 512, N);
        } else {
            updmemb_k<0><<<cdiv(N, 64), 256, 0, stream>>>(pre16, bns, gamma + l * 256,
                                                          beta + l * 256, h16,
                                                          nullptr, nullptr, nullptr,
                                                          nullptr, N);
        }
    }

    gemm_k<2, 4><<<dim3(gx, 1), 256, 0, stream>>>(h16, nullptr, nullptr, wh1p, b_h1,
                                                  nullptr, nullptr, nullptr, wh2p, b_h2,
                                                  (float*)d_out, N, 128, 256);
}

// Round 10
// 352.363 us; speedup vs baseline: 1.4742x; 1.0012x over previous
//
#include <hip/hip_runtime.h>
#include <hip/hip_fp16.h>
#include <cstdint>
#include <cstddef>

using u16 = unsigned short;
using u32 = unsigned int;

typedef _Float16 half8 __attribute__((ext_vector_type(8)));
typedef float f32x4 __attribute__((ext_vector_type(4)));

static inline int cdiv(int a, int b) { return (a + b - 1) / b; }

// ===========================================================================
// prep_k: fused zero-init + weight panelization + rule precompute.
// ===========================================================================

__global__ void prep_k(const float* __restrict__ Wr,
                       const float* __restrict__ Ws, const float* __restrict__ br,
                       const float* __restrict__ W_in, const float* __restrict__ W_h1,
                       const float* __restrict__ W_h2,
                       const float* __restrict__ centers, const float* __restrict__ logsig,
                       u16* __restrict__ wcat,
                       u16* __restrict__ winp, u16* __restrict__ wh1p,
                       u16* __restrict__ wh2p,
                       u16* __restrict__ pcB, float* __restrict__ pccc,
                       int* __restrict__ zerobase, int nzero,
                       int Z, int Wb) {
    const int bid = blockIdx.x;
    const int tid = threadIdx.x;
    if (bid < Z) {                                   // zero-init region
        int i = bid * 256 + tid;
        if (i < nzero) zerobase[i] = 0;
        return;
    }
    if (bid < Z + Wb) {                              // wcat panels [552][256][8] x3 layers
        size_t t = (size_t)(bid - Z) * 256 + tid;
        const size_t PL = 552u * 256u * 8u;
        int l = (int)(t / PL);
        size_t rem = t - (size_t)l * PL;
        int kp = (int)(rem >> 11);
        int o = (int)((rem >> 3) & 255);
        int e = (int)(rem & 7);
        int k = kp * 8 + e;
        float v;
        if (k < 4096)      v = Wr[((((size_t)l * 16 + (k >> 8)) * 256) + (k & 255)) * 256 + o];
        else if (k < 4352) v = Ws[(((size_t)l * 256) + (k - 4096)) * 256 + o];
        else if (k < 4368) v = br[(((size_t)l * 16) + (k - 4352)) * 256 + o];
        else               v = 0.f;
        union { u16 u; _Float16 h; } c; c.h = (_Float16)v;
        wcat[t] = c.u;
        return;
    }
    if (bid < Z + Wb + 128) {                        // panelize W_in (K=128,M=256)
        size_t t = (size_t)(bid - Z - Wb) * 256 + tid;
        int e = (int)(t & 7), o = (int)((t >> 3) & 255);
        int kp = (int)(t >> 11);
        union { u16 u; _Float16 h; } c; c.h = (_Float16)W_in[(size_t)(kp * 8 + e) * 256 + o];
        winp[t] = c.u;
        return;
    }
    if (bid < Z + Wb + 256) {                        // panelize W_h1 (K=256,M=128)
        size_t t = (size_t)(bid - Z - Wb - 128) * 256 + tid;
        int e = (int)(t & 7), o = (int)((t >> 3) & 127);
        int kp = (int)(t >> 10);
        union { u16 u; _Float16 h; } c; c.h = (_Float16)W_h1[(size_t)(kp * 8 + e) * 128 + o];
        wh1p[t] = c.u;
        return;
    }
    if (bid < Z + Wb + 256 + 24) {                   // panelize W_h2 (K=128,M=40->48 pad)
        int t = (bid - Z - Wb - 256) * 256 + tid;    // 16*48*8 = 6144
        int e = t & 7, col = (t >> 3) % 48, p = t / 384;
        int k = p * 8 + e;
        float v = (col < 40) ? W_h2[(size_t)k * 40 + col] : 0.f;
        union { u16 u; _Float16 h; } c; c.h = (_Float16)v;
        wh2p[t] = c.u;
        return;
    }
    {                                                // pc_build: 48 blocks (l*16+r)
        int lr = bid - (Z + Wb + 256 + 24);
        size_t idx = (size_t)lr * 256 + tid;
        float ls = logsig[idx];
        float inv = expf(-2.f * ls);
        float c = centers[idx];
        union { u16 u; _Float16 h; } c1, c2;
        c1.h = (_Float16)inv;
        c2.h = (_Float16)(-2.f * c * inv);
        pcB[(size_t)lr * 512 + tid] = c1.u;          // B[k][r] = inv_s2[r][k], k<256
        pcB[(size_t)lr * 512 + 256 + tid] = c2.u;    // B[256+k][r] = -2 c inv
        __shared__ float sm[256];
        sm[tid] = c * c * inv;
        __syncthreads();
        for (int s = 128; s > 0; s >>= 1) { if (tid < s) sm[tid] += sm[tid + s]; __syncthreads(); }
        if (tid == 0) pccc[lr] = sm[0];
    }
}

// ===========================================================================
// csr_agg_g: gated CSR build (count->scan->scatter, internal grid barrier over
// 256 co-resident blocks — cold path only) + neighbor-mean aggregation.
// Hot path (bany==0): single flag read, exit.
// ===========================================================================

__launch_bounds__(256, 4)
__global__ void csr_agg_g(const int* __restrict__ src, const int* __restrict__ dst,
                          int* __restrict__ deg, int* __restrict__ indptr,
                          int* __restrict__ cursor, float* __restrict__ deginv,
                          int* __restrict__ ssrc, int* __restrict__ csrctr,
                          const int* __restrict__ bflag, int* __restrict__ done,
                          const u16* __restrict__ h16, u16* __restrict__ agg16,
                          int E, int n) {
    if (bflag[511] == 0) return;
    const int tid = threadIdx.x;
    // cold path: build CSR once. 256 blocks, all co-resident (1/CU); monotonic
    // counter barrier (ids 1..3) is safe under full residency.
    if (*done == 0) {
        auto gbar = [&](int id) {
            __threadfence();
            __syncthreads();
            if (tid == 0) {
                atomicAdd(csrctr, 1);
                while (atomicAdd(csrctr, 0) < 256 * id) __builtin_amdgcn_s_sleep(2);
            }
            __syncthreads();
        };
        for (int e = blockIdx.x * 256 + tid; e < E; e += 256 * 256)
            atomicAdd(&deg[dst[e]], 1);
        gbar(1);
        if (blockIdx.x == 0) {                       // 256-thread scan
            const int chunk = (n + 255) >> 8;
            int s0 = tid * chunk, s1 = s0 + chunk; if (s1 > n) s1 = n; if (s0 > n) s0 = n;
            int tot = 0;
            for (int i = s0; i < s1; ++i) tot += atomicAdd(&deg[i], 0);
            __shared__ int sm[256];
            sm[tid] = tot; __syncthreads();
            for (int off = 1; off < 256; off <<= 1) {
                int t = (tid >= off) ? sm[tid - off] : 0;
                __syncthreads(); sm[tid] += t; __syncthreads();
            }
            int base = sm[tid] - tot;
            for (int i = s0; i < s1; ++i) {
                int d = atomicAdd(&deg[i], 0);
                indptr[i] = base; cursor[i] = base;
                deginv[i] = 1.f / (float)(d > 1 ? d : 1);
                base += d;
            }
            if (tid == 255) indptr[n] = sm[255];
        }
        gbar(2);
        for (int e = blockIdx.x * 256 + tid; e < E; e += 256 * 256) {
            int d = dst[e];
            int pos = atomicAdd(&cursor[d], 1);
            ssrc[pos] = src[e];
        }
        gbar(3);
        if (blockIdx.x == 0 && tid == 0) *done = 1;
    }
    // aggregation (grid-stride; per-128-node-block gating)
    int lane = tid & 63, wave = tid >> 6;
    for (int node = blockIdx.x * 4 + wave; node < n; node += 256 * 4) {
        if (bflag[node >> 7] == 0) continue;
        int j0 = indptr[node], j1 = indptr[node + 1];
        float a0 = 0, a1 = 0, a2 = 0, a3 = 0;
        for (int j = j0; j < j1; ++j) {
            int sN = ssrc[j];
            union { uint2 u; _Float16 h[4]; } hv;
            hv.u = *(const uint2*)(h16 + (size_t)sN * 256 + lane * 4);
            a0 += (float)hv.h[0]; a1 += (float)hv.h[1];
            a2 += (float)hv.h[2]; a3 += (float)hv.h[3];
        }
        float di = deginv[node];
        union { uint2 u; _Float16 h[4]; } o;
        o.h[0] = (_Float16)(a0 * di); o.h[1] = (_Float16)(a1 * di);
        o.h[2] = (_Float16)(a2 * di); o.h[3] = (_Float16)(a3 * di);
        *(uint2*)(agg16 + (size_t)node * 256 + lane * 4) = o.u;
    }
}

// ===========================================================================
// MFMA membership (standalone, layer 0): d = [h^2|h] @ pcB + cc; mu = norm.
// ===========================================================================

__launch_bounds__(256)
__global__ void memb_k(const u16* __restrict__ h16, const u16* __restrict__ pcB,
                       const float* __restrict__ pccc,
                       u16* __restrict__ mu16, int* __restrict__ bflag, int n) {
    const int lane = threadIdx.x & 63, wave = threadIdx.x >> 6;
    const int q = lane >> 4, mm = lane & 15;
    const int n0 = (blockIdx.x * 4 + wave) * 16;
    if (n0 >= n) return;
    int nodeA = n0 + mm; if (nodeA >= n) nodeA = n - 1;
    const u16* hrow = h16 + (size_t)nodeA * 256;
    const u16* brow = pcB + (size_t)mm * 512;
    f32x4 acc = (f32x4){0.f, 0.f, 0.f, 0.f};
#pragma unroll
    for (int it = 0; it < 16; ++it) {
        int k = it * 32 + q * 8;
        half8 b = *(const half8*)(brow + k);
        half8 a;
        if (k < 256) {
            a = *(const half8*)(hrow + k);
            a = a * a;
        } else {
            a = *(const half8*)(hrow + (k - 256));
        }
        acc = __builtin_amdgcn_mfma_f32_16x16x32_f16(a, b, acc, 0, 0, 0);
    }
    float cc = pccc[mm];
    bool any = false;
#pragma unroll
    for (int r = 0; r < 4; ++r) {
        float d = acc[r] + cc;
        float f = expf(-0.5f * d);
        float s = f;
        s += __shfl_xor(s, 1); s += __shfl_xor(s, 2);
        s += __shfl_xor(s, 4); s += __shfl_xor(s, 8);
        int node = n0 + q * 4 + r;
        if (node < n) {
            union { u16 u; _Float16 h; } c2;
            c2.h = (_Float16)(f / (s + 1e-12f));
            mu16[(size_t)node * 16 + mm] = c2.u;
            if (s > 0.f) any = true;
        }
    }
    if (any && mm == 0) {
        atomicOr(&bflag[n0 >> 7], 1);
        atomicOr(&bflag[511], 1);
    }
}

// ===========================================================================
// Unified f16 MFMA GEMM. 128x128 tile, BK=64, 256 threads (4 waves).
// MODE 0: h16 = relu(x @ Winp + b_in)  — A is raw f32 x, converted in staging.
// MODE 1: pre16 = [mu*agg | h | mu]@Wcat + b_self; BN partial sums per rowblock.
// MODE 2: relu(h16 @ Wh1p + b_h1) kept in LDS, fused head GEMM + softmax -> outF.
// Epilogue (0/1): tile -> LDS (stride 136) -> coalesced uint4 global writes.
// ===========================================================================

template <int MODE, int NCHUNK>
__launch_bounds__(256, 4)
__global__ void gemm_k(const u16* __restrict__ A, const u16* __restrict__ A2,
                       const u16* __restrict__ MU, const u16* __restrict__ Bp,
                       const float* __restrict__ bias, const int* __restrict__ bflag,
                       u16* __restrict__ outH, float* __restrict__ partial,
                       const u16* __restrict__ wh2, const float* __restrict__ bh2,
                       float* __restrict__ outF,
                       int nrows, int mcols, int astride) {
    __shared__ __align__(16) u16 lds[17408];   // staging (16K u16) / out tile 128x136
    __shared__ float bnbuf[512];
    u16* lA = lds;
    u16* lB = lds + 8192;
    const int tid = threadIdx.x;
    const int row0 = blockIdx.x * 128;
    const int c0 = blockIdx.y * 128;
    const int lane = tid & 63;
    const int q = lane >> 4, mm = lane & 15;
    const int wave = tid >> 6;
    const int wm = wave >> 1, wn = wave & 1;

    f32x4 acc[4][4];
#pragma unroll
    for (int i = 0; i < 4; ++i)
#pragma unroll
        for (int j = 0; j < 4; ++j) acc[i][j] = (f32x4){0.f, 0.f, 0.f, 0.f};

    int cb = 0, cbEnd = NCHUNK;
    if (MODE == 1 && bflag[blockIdx.x] == 0) { cb = 64; cbEnd = 68; }  // mu==0: fuzzy+mu K exact-zero

    for (; cb < cbEnd; ++cb) {
#pragma unroll
        for (int it = 0; it < 4; ++it) {
            int idx = it * 256 + tid;
            int p = idx >> 7, col = idx & 127;
            uint4 v = *(const uint4*)(Bp + (((size_t)(cb * 8 + p)) * mcols + c0 + col) * 8);
            *(uint4*)(lB + (size_t)idx * 8) = v;
        }
#pragma unroll
        for (int it = 0; it < 4; ++it) {
            int idx = it * 256 + tid;
            int p = idx >> 7, row = idx & 127;
            int grow = row0 + row; if (grow >= nrows) grow = nrows - 1;
            uint4 v;
            if (MODE == 0) {
                const float* xr = (const float*)A + (size_t)grow * 128 + cb * 64 + (p << 3);
                float4 f0 = *(const float4*)xr;
                float4 f1 = *(const float4*)(xr + 4);
                union { uint4 u4; _Float16 h[8]; } cv;
                cv.h[0] = (_Float16)f0.x; cv.h[1] = (_Float16)f0.y;
                cv.h[2] = (_Float16)f0.z; cv.h[3] = (_Float16)f0.w;
                cv.h[4] = (_Float16)f1.x; cv.h[5] = (_Float16)f1.y;
                cv.h[6] = (_Float16)f1.z; cv.h[7] = (_Float16)f1.w;
                v = cv.u4;
            } else if (MODE == 2) {
                v = *(const uint4*)(A + (size_t)grow * astride + cb * 64 + p * 8);
            } else {
                if (cb < 64) {
                    int r = cb >> 2;
                    int i0 = ((cb & 3) << 6) + (p << 3);
                    v = *(const uint4*)(A + (size_t)grow * 256 + i0);
                    union { u16 u; _Float16 h; } mu; mu.u = MU[(size_t)grow * 16 + r];
                    union { uint4 u4; _Float16 h[8]; } wv; wv.u4 = v;
#pragma unroll
                    for (int j = 0; j < 8; ++j) wv.h[j] = wv.h[j] * mu.h;
                    v = wv.u4;
                } else if (cb < 68) {
                    int i0 = ((cb - 64) << 6) + (p << 3);
                    v = *(const uint4*)(A2 + (size_t)grow * 256 + i0);
                } else {
                    int j0 = p << 3;
                    if (j0 < 16) v = *(const uint4*)(MU + (size_t)grow * 16 + j0);
                    else v = (uint4){0, 0, 0, 0};
                }
            }
            *(uint4*)(lA + (size_t)idx * 8) = v;
        }
        __syncthreads();
#pragma unroll
        for (int kc = 0; kc < 2; ++kc) {
            int pp = kc * 4 + q;
            half8 af[4], bf[4];
#pragma unroll
            for (int mt = 0; mt < 4; ++mt)
                af[mt] = *(const half8*)(lA + ((size_t)pp * 128 + wm * 64 + mt * 16 + mm) * 8);
#pragma unroll
            for (int nt = 0; nt < 4; ++nt)
                bf[nt] = *(const half8*)(lB + ((size_t)pp * 128 + wn * 64 + nt * 16 + mm) * 8);
#pragma unroll
            for (int mt = 0; mt < 4; ++mt)
#pragma unroll
                for (int nt = 0; nt < 4; ++nt)
                    acc[mt][nt] = __builtin_amdgcn_mfma_f32_16x16x32_f16(af[mt], bf[nt], acc[mt][nt], 0, 0, 0);
        }
        __syncthreads();
    }

    // epilogue: C/D layout col=lane&15, row=q*4+reg. Tile -> LDS (stride 136).
#pragma unroll
    for (int nt = 0; nt < 4; ++nt) {
        const int cl = wn * 64 + nt * 16 + mm;
        const int gcol = c0 + cl;
        float s = 0.f, ss = 0.f;
#pragma unroll
        for (int mt = 0; mt < 4; ++mt) {
#pragma unroll
            for (int r = 0; r < 4; ++r) {
                int row = wm * 64 + mt * 16 + q * 4 + r;
                float v = acc[mt][nt][r] + bias[gcol];
                if (MODE != 1) v = fmaxf(v, 0.f);
                union { u16 u; _Float16 h; } cc; cc.h = (_Float16)v;
                lds[row * 136 + cl] = cc.u;
                if (MODE == 1 && row0 + row < nrows) { s += v; ss += v * v; }
            }
        }
        if (MODE == 1) {
            s += __shfl_xor(s, 16);  s += __shfl_xor(s, 32);
            ss += __shfl_xor(ss, 16); ss += __shfl_xor(ss, 32);
            if (q == 0) {
                bnbuf[(wm * 128 + cl) * 2 + 0] = s;
                bnbuf[(wm * 128 + cl) * 2 + 1] = ss;
            }
        }
    }
    __syncthreads();

    if (MODE != 2) {
        int nr = nrows - row0; if (nr > 128) nr = 128;
#pragma unroll
        for (int it = 0; it < 8; ++it) {
            int idx = it * 256 + tid;        // 0..2047 chunks of 16B
            int row = idx >> 4, cp = idx & 15;
            if (row < nr) {
                uint4 v = *(const uint4*)(lds + row * 136 + cp * 8);
                *(uint4*)(outH + (size_t)(row0 + row) * mcols + c0 + cp * 8) = v;
            }
        }
        if (MODE == 1) {
            int cl2 = tid >> 1, comp = tid & 1;
            float v = bnbuf[cl2 * 2 + comp] + bnbuf[(128 + cl2) * 2 + comp];
            partial[(size_t)blockIdx.x * 512 + comp * 256 + c0 + cl2] = v;
        }
    } else {
        // fused head: q-tile (128x128, stride 136) @ wh2 (48-padded) + softmax
        const bool c2ok = (mm < 8);
        float b0 = bh2[mm], b1 = bh2[16 + mm];
        float b2 = c2ok ? bh2[32 + mm] : 0.f;
#pragma unroll
        for (int half = 0; half < 2; ++half) {
            int rbase = half * 64 + wave * 16;    // 16-node group
            f32x4 hacc[3];
#pragma unroll
            for (int t = 0; t < 3; ++t) hacc[t] = (f32x4){0.f, 0.f, 0.f, 0.f};
#pragma unroll
            for (int c = 0; c < 4; ++c) {
                half8 a = *(const half8*)(lds + (rbase + mm) * 136 + c * 32 + q * 8);
#pragma unroll
                for (int t = 0; t < 3; ++t) {
                    half8 b = *(const half8*)(wh2 + ((size_t)(c * 4 + q) * 48 + t * 16 + mm) * 8);
                    hacc[t] = __builtin_amdgcn_mfma_f32_16x16x32_f16(a, b, hacc[t], 0, 0, 0);
                }
            }
#pragma unroll
            for (int r = 0; r < 4; ++r) {
                int node = row0 + rbase + q * 4 + r;
                float v0 = hacc[0][r] + b0;
                float v1 = hacc[1][r] + b1;
                float v2 = c2ok ? (hacc[2][r] + b2) : -3e38f;
                float m = fmaxf(fmaxf(v0, v1), v2);
                m = fmaxf(m, __shfl_xor(m, 1)); m = fmaxf(m, __shfl_xor(m, 2));
                m = fmaxf(m, __shfl_xor(m, 4)); m = fmaxf(m, __shfl_xor(m, 8));
                float e0 = expf(v0 - m), e1 = expf(v1 - m);
                float e2 = c2ok ? expf(v2 - m) : 0.f;
                float s = e0 + e1 + e2;
                s += __shfl_xor(s, 1); s += __shfl_xor(s, 2);
                s += __shfl_xor(s, 4); s += __shfl_xor(s, 8);
                float is = 1.f / s;
                if (node < nrows) {
                    float* op = outF + (size_t)node * 40;
                    op[mm] = e0 * is;
                    op[16 + mm] = e1 * is;
                    if (c2ok) op[32 + mm] = e2 * is;
                }
            }
        }
    }
}

// ===========================================================================
// updmemb_k: fused BN-reduce (blocks 0-31) -> ab finalize -> release-gate ->
// residual update (+ optional next-layer membership). 782 blocks all
// co-resident (0 LDS, ~50 VGPR -> 8 blocks/CU capacity), so the release
// spin cannot deadlock.
// ===========================================================================

template <int DOMEMB>
__launch_bounds__(256)
__global__ void updmemb_k(const u16* __restrict__ pre16, const float* __restrict__ partial,
                          float* __restrict__ bnsum,
                          const float* __restrict__ gamma, const float* __restrict__ beta,
                          float* __restrict__ ab, int* __restrict__ bnctr,
                          int* __restrict__ bnrel,
                          u16* __restrict__ h16,
                          const u16* __restrict__ pcB, const float* __restrict__ pccc,
                          u16* __restrict__ mu16, int* __restrict__ bflag,
                          int n, int gx) {
    const int tid = threadIdx.x;
    // phase 1: BN reduction by blocks 0..31
    if (blockIdx.x < 32) {
        int o = (blockIdx.x & 1) * 256 + tid;
        int g = blockIdx.x >> 1;
        float s = 0.f;
        for (int r = g; r < gx; r += 16) s += partial[(size_t)r * 512 + o];
        atomicAdd(&bnsum[o], s);
        __threadfence();
        __shared__ int last;
        if (tid == 0) last = (atomicAdd(bnctr, 1) == 31);
        __syncthreads();
        if (last) {
            float su = atomicAdd(&bnsum[tid], 0.f);
            float sq = atomicAdd(&bnsum[256 + tid], 0.f);
            float invn = 1.f / (float)n;
            float m = su * invn;
            float al = gamma[tid] * rsqrtf(sq * invn - m * m + 1e-5f);
            ab[tid] = al;
            ab[256 + tid] = beta[tid] - m * al;
            __threadfence();
            __syncthreads();
            if (tid == 0) atomicExch(bnrel, 1);
        }
    }
    // phase 2: all blocks wait for ab
    if (tid == 0) {
        while (atomicAdd(bnrel, 0) == 0) __builtin_amdgcn_s_sleep(2);
    }
    __syncthreads();

    // phase 3: residual update (+membership)
    const int lane = tid & 63, wave = tid >> 6;
    const int q = lane >> 4, mm = lane & 15;
    const int n0 = (blockIdx.x * 4 + wave) * 16;
    if (n0 >= n) return;
    const int node = n0 + mm;
    const bool valid = node < n;
    const int nodeC = valid ? node : n - 1;
    const size_t base = (size_t)nodeC * 256 + q * 8;

    half8 v16[8];
#pragma unroll
    for (int b = 0; b < 8; ++b) {
        int c = b * 32 + q * 8;
        float4 alA = *(const float4*)(ab + c);
        float4 alB = *(const float4*)(ab + c + 4);
        float4 shA = *(const float4*)(ab + 256 + c);
        float4 shB = *(const float4*)(ab + 256 + c + 4);
        float aarr[8] = {alA.x, alA.y, alA.z, alA.w, alB.x, alB.y, alB.z, alB.w};
        float harr[8] = {shA.x, shA.y, shA.z, shA.w, shB.x, shB.y, shB.z, shB.w};
        union { uint4 u; _Float16 hh[8]; } p, hv, o;
        p.u  = *(const uint4*)(pre16 + base + b * 32);
        hv.u = *(const uint4*)(h16 + base + b * 32);
#pragma unroll
        for (int j = 0; j < 8; ++j) {
            float v = (float)hv.hh[j] + fmaxf((float)p.hh[j] * aarr[j] + harr[j], 0.f);
            o.hh[j] = (_Float16)v;
        }
        if (valid) *(uint4*)(h16 + base + b * 32) = o.u;
        v16[b] = *(half8*)&o;
    }

    if (DOMEMB) {
        const u16* brow = pcB + (size_t)mm * 512;
        f32x4 acc = (f32x4){0.f, 0.f, 0.f, 0.f};
#pragma unroll
        for (int it = 0; it < 16; ++it) {
            half8 a = v16[it & 7];
            if (it < 8) a = a * a;
            half8 bb = *(const half8*)(brow + it * 32 + q * 8);
            acc = __builtin_amdgcn_mfma_f32_16x16x32_f16(a, bb, acc, 0, 0, 0);
        }
        float cc = pccc[mm];
        bool any = false;
#pragma unroll
        for (int r = 0; r < 4; ++r) {
            float d = acc[r] + cc;
            float f = expf(-0.5f * d);
            float s = f;
            s += __shfl_xor(s, 1); s += __shfl_xor(s, 2);
            s += __shfl_xor(s, 4); s += __shfl_xor(s, 8);
            int nd = n0 + q * 4 + r;
            if (nd < n) {
                union { u16 u; _Float16 h; } c2;
                c2.h = (_Float16)(f / (s + 1e-12f));
                mu16[(size_t)nd * 16 + mm] = c2.u;
                if (s > 0.f) any = true;
            }
        }
        if (any && mm == 0) {
            atomicOr(&bflag[n0 >> 7], 1);
            atomicOr(&bflag[511], 1);
        }
    }
}

// ===========================================================================
// Launch
// ===========================================================================

extern "C" void kernel_launch(void* const* d_in, const int* in_sizes, int n_in,
                              void* d_out, int out_size, void* d_ws, size_t ws_size,
                              hipStream_t stream) {
    const float* x       = (const float*)d_in[0];
    const int*   ei      = (const int*)d_in[1];
    const float* W_in    = (const float*)d_in[2];
    const float* b_in    = (const float*)d_in[3];
    const float* centers = (const float*)d_in[4];
    const float* logsig  = (const float*)d_in[5];
    const float* W_rule  = (const float*)d_in[6];
    const float* b_rule  = (const float*)d_in[7];
    const float* W_self  = (const float*)d_in[8];
    const float* b_self  = (const float*)d_in[9];
    const float* gamma   = (const float*)d_in[10];
    const float* beta    = (const float*)d_in[11];
    const float* W_h1    = (const float*)d_in[12];
    const float* b_h1    = (const float*)d_in[13];
    const float* W_h2    = (const float*)d_in[14];
    const float* b_h2    = (const float*)d_in[15];

    const int N = in_sizes[0] / 128;
    const int E = in_sizes[1] / 2;
    const int* e_src = ei;
    const int* e_dst = ei + E;

    char* w = (char*)d_ws;
    size_t off = 0;
    auto alloc = [&](size_t bytes) -> void* {
        void* p = w + off;
        off = (off + bytes + 255) & ~(size_t)255;
        return p;
    };

    const int gx = cdiv(N, 128);

    u16*   h16    = (u16*)  alloc((size_t)N * 256 * 2);
    u16*   pre16  = (u16*)  alloc((size_t)N * 256 * 2);
    u16*   agg16  = (u16*)  alloc((size_t)N * 256 * 2);
    u16*   mu16   = (u16*)  alloc((size_t)N * 16 * 2);
    u16*   wcat   = (u16*)  alloc((size_t)3 * 552 * 256 * 8 * 2);
    u16*   winp   = (u16*)  alloc((size_t)16 * 256 * 8 * 2);
    u16*   wh1p   = (u16*)  alloc((size_t)32 * 128 * 8 * 2);
    u16*   wh2p   = (u16*)  alloc((size_t)16 * 48 * 8 * 2);
    u16*   pcB    = (u16*)  alloc((size_t)48 * 512 * 2);
    float* pccc   = (float*)alloc((size_t)48 * 4);
    int*   indptr = (int*)  alloc((size_t)(N + 1) * 4);
    int*   cursor = (int*)  alloc((size_t)N * 4);
    float* deginv = (float*)alloc((size_t)N * 4);
    int*   ssrc   = (int*)  alloc((size_t)E * 4);
    float* partial= (float*)alloc((size_t)gx * 512 * 4);
    float* abA    = (float*)alloc((size_t)3 * 512 * 4);
    // zero region: [deg N][bflag 3*512][bnsum 3*512][done, csrctr, bnctr[3], bnrel[3]]
    const int nzero = N + 3 * 512 + 3 * 512 + 16;
    int*   zerob  = (int*)  alloc((size_t)nzero * 4);
    int*   deg    = zerob;
    int*   bflagA = zerob + N;
    float* bnsumA = (float*)(zerob + N + 3 * 512);
    int*   misc   = zerob + N + 3 * 512 + 3 * 512;
    int*   done   = misc;
    int*   csrctr = misc + 1;
    int*   bnctr  = misc + 2;   // [3]
    int*   bnrel  = misc + 5;   // [3]

    const int Z = cdiv(nzero, 256);
    const int Wb = 3 * 552 * 256 * 8 / 256;   // 13248
    const int prep_grid = Z + Wb + 128 + 128 + 24 + 48;

    prep_k<<<prep_grid, 256, 0, stream>>>(W_rule, W_self, b_rule, W_in, W_h1, W_h2,
                                          centers, logsig, wcat, winp, wh1p, wh2p,
                                          pcB, pccc, zerob, nzero, Z, Wb);

    gemm_k<0, 2><<<dim3(gx, 2), 256, 0, stream>>>((const u16*)x, nullptr, nullptr, winp,
                                                  b_in, nullptr, h16, nullptr, nullptr,
                                                  nullptr, nullptr, N, 256, 128);
    memb_k<<<cdiv(N, 64), 256, 0, stream>>>(h16, pcB, pccc, mu16, bflagA, N);

    for (int l = 0; l < 3; ++l) {
        int* bf = bflagA + l * 512;
        float* bns = bnsumA + l * 512;
        csr_agg_g<<<256, 256, 0, stream>>>(e_src, e_dst, deg, indptr, cursor, deginv,
                                           ssrc, csrctr, bf, done, h16, agg16, E, N);
        gemm_k<1, 69><<<dim3(gx, 2), 256, 0, stream>>>(agg16, h16, mu16,
                                                       wcat + (size_t)l * 552 * 256 * 8,
                                                       b_self + l * 256, bf, pre16,
                                                       partial, nullptr, nullptr, nullptr,
                                                       N, 256, 0);
        if (l < 2) {
            updmemb_k<1><<<cdiv(N, 64), 256, 0, stream>>>(pre16, partial, bns,
                                                          gamma + l * 256, beta + l * 256,
                                                          abA + l * 512, bnctr + l, bnrel + l,
                                                          h16,
                                                          pcB + (size_t)(l + 1) * 16 * 512,
                                                          pccc + (l + 1) * 16, mu16,
                                                          bflagA + (l + 1) * 512, N, gx);
        } else {
            updmemb_k<0><<<cdiv(N, 64), 256, 0, stream>>>(pre16, partial, bns,
                                                          gamma + l * 256, beta + l * 256,
                                                          abA + l * 512, bnctr + l, bnrel + l,
                                                          h16, nullptr, nullptr, nullptr,
                                                          nullptr, N, gx);
        }
    }

    gemm_k<2, 4><<<dim3(gx, 1), 256, 0, stream>>>(h16, nullptr, nullptr, wh1p, b_h1,
                                                  nullptr, nullptr, nullptr, wh2p, b_h2,
                                                  (float*)d_out, N, 128, 256);
}

// Round 11
// 333.318 us; speedup vs baseline: 1.5585x; 1.0571x over previous
//
#include <hip/hip_runtime.h>
#include <hip/hip_fp16.h>
#include <cstdint>
#include <cstddef>

using u16 = unsigned short;
using u32 = unsigned int;

typedef _Float16 half8 __attribute__((ext_vector_type(8)));
typedef float f32x4 __attribute__((ext_vector_type(4)));

static inline int cdiv(int a, int b) { return (a + b - 1) / b; }

// ===========================================================================
// prep_k: fused zero-init + weight panelization + rule precompute.
// ===========================================================================

__global__ void prep_k(const float* __restrict__ Wr,
                       const float* __restrict__ Ws, const float* __restrict__ br,
                       const float* __restrict__ W_in, const float* __restrict__ W_h1,
                       const float* __restrict__ W_h2,
                       const float* __restrict__ centers, const float* __restrict__ logsig,
                       u16* __restrict__ wcat,
                       u16* __restrict__ winp, u16* __restrict__ wh1p,
                       u16* __restrict__ wh2p,
                       u16* __restrict__ pcB, float* __restrict__ pccc,
                       int* __restrict__ zerobase, int nzero,
                       int Z, int Wb) {
    const int bid = blockIdx.x;
    const int tid = threadIdx.x;
    if (bid < Z) {                                   // zero-init region
        int i = bid * 256 + tid;
        if (i < nzero) zerobase[i] = 0;
        return;
    }
    if (bid < Z + Wb) {                              // wcat panels [552][256][8] x3 layers
        size_t t = (size_t)(bid - Z) * 256 + tid;
        const size_t PL = 552u * 256u * 8u;
        int l = (int)(t / PL);
        size_t rem = t - (size_t)l * PL;
        int kp = (int)(rem >> 11);
        int o = (int)((rem >> 3) & 255);
        int e = (int)(rem & 7);
        int k = kp * 8 + e;
        float v;
        if (k < 4096)      v = Wr[((((size_t)l * 16 + (k >> 8)) * 256) + (k & 255)) * 256 + o];
        else if (k < 4352) v = Ws[(((size_t)l * 256) + (k - 4096)) * 256 + o];
        else if (k < 4368) v = br[(((size_t)l * 16) + (k - 4352)) * 256 + o];
        else               v = 0.f;
        union { u16 u; _Float16 h; } c; c.h = (_Float16)v;
        wcat[t] = c.u;
        return;
    }
    if (bid < Z + Wb + 128) {                        // panelize W_in (K=128,M=256)
        size_t t = (size_t)(bid - Z - Wb) * 256 + tid;
        int e = (int)(t & 7), o = (int)((t >> 3) & 255);
        int kp = (int)(t >> 11);
        union { u16 u; _Float16 h; } c; c.h = (_Float16)W_in[(size_t)(kp * 8 + e) * 256 + o];
        winp[t] = c.u;
        return;
    }
    if (bid < Z + Wb + 256) {                        // panelize W_h1 (K=256,M=128)
        size_t t = (size_t)(bid - Z - Wb - 128) * 256 + tid;
        int e = (int)(t & 7), o = (int)((t >> 3) & 127);
        int kp = (int)(t >> 10);
        union { u16 u; _Float16 h; } c; c.h = (_Float16)W_h1[(size_t)(kp * 8 + e) * 128 + o];
        wh1p[t] = c.u;
        return;
    }
    if (bid < Z + Wb + 256 + 24) {                   // panelize W_h2 (K=128,M=40->48 pad)
        int t = (bid - Z - Wb - 256) * 256 + tid;    // 16*48*8 = 6144
        int e = t & 7, col = (t >> 3) % 48, p = t / 384;
        int k = p * 8 + e;
        float v = (col < 40) ? W_h2[(size_t)k * 40 + col] : 0.f;
        union { u16 u; _Float16 h; } c; c.h = (_Float16)v;
        wh2p[t] = c.u;
        return;
    }
    {                                                // pc_build: 48 blocks (l*16+r)
        int lr = bid - (Z + Wb + 256 + 24);
        size_t idx = (size_t)lr * 256 + tid;
        float ls = logsig[idx];
        float inv = expf(-2.f * ls);
        float c = centers[idx];
        union { u16 u; _Float16 h; } c1, c2;
        c1.h = (_Float16)inv;
        c2.h = (_Float16)(-2.f * c * inv);
        pcB[(size_t)lr * 512 + tid] = c1.u;          // B[k][r] = inv_s2[r][k], k<256
        pcB[(size_t)lr * 512 + 256 + tid] = c2.u;    // B[256+k][r] = -2 c inv
        __shared__ float sm[256];
        sm[tid] = c * c * inv;
        __syncthreads();
        for (int s = 128; s > 0; s >>= 1) { if (tid < s) sm[tid] += sm[tid + s]; __syncthreads(); }
        if (tid == 0) pccc[lr] = sm[0];
    }
}

// ===========================================================================
// csr_agg_g: gated CSR build (count->scan->scatter, internal grid barrier over
// 256 co-resident blocks — cold path only) + neighbor-mean aggregation.
// Hot path (bany==0): single flag read, exit.
// ===========================================================================

__launch_bounds__(256, 4)
__global__ void csr_agg_g(const int* __restrict__ src, const int* __restrict__ dst,
                          int* __restrict__ deg, int* __restrict__ indptr,
                          int* __restrict__ cursor, float* __restrict__ deginv,
                          int* __restrict__ ssrc, int* __restrict__ csrctr,
                          const int* __restrict__ bflag, int* __restrict__ done,
                          const u16* __restrict__ h16, u16* __restrict__ agg16,
                          int E, int n) {
    if (bflag[511] == 0) return;
    const int tid = threadIdx.x;
    if (*done == 0) {
        auto gbar = [&](int id) {
            __threadfence();
            __syncthreads();
            if (tid == 0) {
                atomicAdd(csrctr, 1);
                while (atomicAdd(csrctr, 0) < 256 * id) __builtin_amdgcn_s_sleep(2);
            }
            __syncthreads();
        };
        for (int e = blockIdx.x * 256 + tid; e < E; e += 256 * 256)
            atomicAdd(&deg[dst[e]], 1);
        gbar(1);
        if (blockIdx.x == 0) {                       // 256-thread scan
            const int chunk = (n + 255) >> 8;
            int s0 = tid * chunk, s1 = s0 + chunk; if (s1 > n) s1 = n; if (s0 > n) s0 = n;
            int tot = 0;
            for (int i = s0; i < s1; ++i) tot += atomicAdd(&deg[i], 0);
            __shared__ int sm[256];
            sm[tid] = tot; __syncthreads();
            for (int off = 1; off < 256; off <<= 1) {
                int t = (tid >= off) ? sm[tid - off] : 0;
                __syncthreads(); sm[tid] += t; __syncthreads();
            }
            int base = sm[tid] - tot;
            for (int i = s0; i < s1; ++i) {
                int d = atomicAdd(&deg[i], 0);
                indptr[i] = base; cursor[i] = base;
                deginv[i] = 1.f / (float)(d > 1 ? d : 1);
                base += d;
            }
            if (tid == 255) indptr[n] = sm[255];
        }
        gbar(2);
        for (int e = blockIdx.x * 256 + tid; e < E; e += 256 * 256) {
            int d = dst[e];
            int pos = atomicAdd(&cursor[d], 1);
            ssrc[pos] = src[e];
        }
        gbar(3);
        if (blockIdx.x == 0 && tid == 0) *done = 1;
    }
    // aggregation (grid-stride; per-128-node-block gating)
    int lane = tid & 63, wave = tid >> 6;
    for (int node = blockIdx.x * 4 + wave; node < n; node += 256 * 4) {
        if (bflag[node >> 7] == 0) continue;
        int j0 = indptr[node], j1 = indptr[node + 1];
        float a0 = 0, a1 = 0, a2 = 0, a3 = 0;
        for (int j = j0; j < j1; ++j) {
            int sN = ssrc[j];
            union { uint2 u; _Float16 h[4]; } hv;
            hv.u = *(const uint2*)(h16 + (size_t)sN * 256 + lane * 4);
            a0 += (float)hv.h[0]; a1 += (float)hv.h[1];
            a2 += (float)hv.h[2]; a3 += (float)hv.h[3];
        }
        float di = deginv[node];
        union { uint2 u; _Float16 h[4]; } o;
        o.h[0] = (_Float16)(a0 * di); o.h[1] = (_Float16)(a1 * di);
        o.h[2] = (_Float16)(a2 * di); o.h[3] = (_Float16)(a3 * di);
        *(uint2*)(agg16 + (size_t)node * 256 + lane * 4) = o.u;
    }
}

// ===========================================================================
// MFMA membership (standalone, layer 0): d = [h^2|h] @ pcB + cc; mu = norm.
// ===========================================================================

__launch_bounds__(256)
__global__ void memb_k(const u16* __restrict__ h16, const u16* __restrict__ pcB,
                       const float* __restrict__ pccc,
                       u16* __restrict__ mu16, int* __restrict__ bflag, int n) {
    const int lane = threadIdx.x & 63, wave = threadIdx.x >> 6;
    const int q = lane >> 4, mm = lane & 15;
    const int n0 = (blockIdx.x * 4 + wave) * 16;
    if (n0 >= n) return;
    int nodeA = n0 + mm; if (nodeA >= n) nodeA = n - 1;
    const u16* hrow = h16 + (size_t)nodeA * 256;
    const u16* brow = pcB + (size_t)mm * 512;
    f32x4 acc = (f32x4){0.f, 0.f, 0.f, 0.f};
#pragma unroll
    for (int it = 0; it < 16; ++it) {
        int k = it * 32 + q * 8;
        half8 b = *(const half8*)(brow + k);
        half8 a;
        if (k < 256) {
            a = *(const half8*)(hrow + k);
            a = a * a;
        } else {
            a = *(const half8*)(hrow + (k - 256));
        }
        acc = __builtin_amdgcn_mfma_f32_16x16x32_f16(a, b, acc, 0, 0, 0);
    }
    float cc = pccc[mm];
    bool any = false;
#pragma unroll
    for (int r = 0; r < 4; ++r) {
        float d = acc[r] + cc;
        float f = expf(-0.5f * d);
        float s = f;
        s += __shfl_xor(s, 1); s += __shfl_xor(s, 2);
        s += __shfl_xor(s, 4); s += __shfl_xor(s, 8);
        int node = n0 + q * 4 + r;
        if (node < n) {
            union { u16 u; _Float16 h; } c2;
            c2.h = (_Float16)(f / (s + 1e-12f));
            mu16[(size_t)node * 16 + mm] = c2.u;
            if (s > 0.f) any = true;
        }
    }
    if (any && mm == 0) {
        atomicOr(&bflag[n0 >> 7], 1);
        atomicOr(&bflag[511], 1);
    }
}

// ===========================================================================
// Unified f16 MFMA GEMM. 128x128 tile, BK=64, 256 threads (4 waves).
// MODE 0: h16 = relu(x @ Winp + b_in)  — A is raw f32 x, converted in staging.
// MODE 1: pre16 = [mu*agg | h | mu]@Wcat + b_self; BN partial sums per rowblock.
// MODE 2: relu(h16 @ Wh1p + b_h1) kept in LDS, fused head GEMM + softmax -> outF.
// Epilogue (0/1): tile -> LDS (stride 136) -> coalesced uint4 global writes.
// ===========================================================================

template <int MODE, int NCHUNK>
__launch_bounds__(256, 4)
__global__ void gemm_k(const u16* __restrict__ A, const u16* __restrict__ A2,
                       const u16* __restrict__ MU, const u16* __restrict__ Bp,
                       const float* __restrict__ bias, const int* __restrict__ bflag,
                       u16* __restrict__ outH, float* __restrict__ partial,
                       const u16* __restrict__ wh2, const float* __restrict__ bh2,
                       float* __restrict__ outF,
                       int nrows, int mcols, int astride) {
    __shared__ __align__(16) u16 lds[17408];   // staging (16K u16) / out tile 128x136
    __shared__ float bnbuf[512];
    u16* lA = lds;
    u16* lB = lds + 8192;
    const int tid = threadIdx.x;
    const int row0 = blockIdx.x * 128;
    const int c0 = blockIdx.y * 128;
    const int lane = tid & 63;
    const int q = lane >> 4, mm = lane & 15;
    const int wave = tid >> 6;
    const int wm = wave >> 1, wn = wave & 1;

    f32x4 acc[4][4];
#pragma unroll
    for (int i = 0; i < 4; ++i)
#pragma unroll
        for (int j = 0; j < 4; ++j) acc[i][j] = (f32x4){0.f, 0.f, 0.f, 0.f};

    int cb = 0, cbEnd = NCHUNK;
    if (MODE == 1 && bflag[blockIdx.x] == 0) { cb = 64; cbEnd = 68; }  // mu==0: fuzzy+mu K exact-zero

    for (; cb < cbEnd; ++cb) {
#pragma unroll
        for (int it = 0; it < 4; ++it) {
            int idx = it * 256 + tid;
            int p = idx >> 7, col = idx & 127;
            uint4 v = *(const uint4*)(Bp + (((size_t)(cb * 8 + p)) * mcols + c0 + col) * 8);
            *(uint4*)(lB + (size_t)idx * 8) = v;
        }
#pragma unroll
        for (int it = 0; it < 4; ++it) {
            int idx = it * 256 + tid;
            int p = idx >> 7, row = idx & 127;
            int grow = row0 + row; if (grow >= nrows) grow = nrows - 1;
            uint4 v;
            if (MODE == 0) {
                const float* xr = (const float*)A + (size_t)grow * 128 + cb * 64 + (p << 3);
                float4 f0 = *(const float4*)xr;
                float4 f1 = *(const float4*)(xr + 4);
                union { uint4 u4; _Float16 h[8]; } cv;
                cv.h[0] = (_Float16)f0.x; cv.h[1] = (_Float16)f0.y;
                cv.h[2] = (_Float16)f0.z; cv.h[3] = (_Float16)f0.w;
                cv.h[4] = (_Float16)f1.x; cv.h[5] = (_Float16)f1.y;
                cv.h[6] = (_Float16)f1.z; cv.h[7] = (_Float16)f1.w;
                v = cv.u4;
            } else if (MODE == 2) {
                v = *(const uint4*)(A + (size_t)grow * astride + cb * 64 + p * 8);
            } else {
                if (cb < 64) {
                    int r = cb >> 2;
                    int i0 = ((cb & 3) << 6) + (p << 3);
                    v = *(const uint4*)(A + (size_t)grow * 256 + i0);
                    union { u16 u; _Float16 h; } mu; mu.u = MU[(size_t)grow * 16 + r];
                    union { uint4 u4; _Float16 h[8]; } wv; wv.u4 = v;
#pragma unroll
                    for (int j = 0; j < 8; ++j) wv.h[j] = wv.h[j] * mu.h;
                    v = wv.u4;
                } else if (cb < 68) {
                    int i0 = ((cb - 64) << 6) + (p << 3);
                    v = *(const uint4*)(A2 + (size_t)grow * 256 + i0);
                } else {
                    int j0 = p << 3;
                    if (j0 < 16) v = *(const uint4*)(MU + (size_t)grow * 16 + j0);
                    else v = (uint4){0, 0, 0, 0};
                }
            }
            *(uint4*)(lA + (size_t)idx * 8) = v;
        }
        __syncthreads();
#pragma unroll
        for (int kc = 0; kc < 2; ++kc) {
            int pp = kc * 4 + q;
            half8 af[4], bf[4];
#pragma unroll
            for (int mt = 0; mt < 4; ++mt)
                af[mt] = *(const half8*)(lA + ((size_t)pp * 128 + wm * 64 + mt * 16 + mm) * 8);
#pragma unroll
            for (int nt = 0; nt < 4; ++nt)
                bf[nt] = *(const half8*)(lB + ((size_t)pp * 128 + wn * 64 + nt * 16 + mm) * 8);
#pragma unroll
            for (int mt = 0; mt < 4; ++mt)
#pragma unroll
                for (int nt = 0; nt < 4; ++nt)
                    acc[mt][nt] = __builtin_amdgcn_mfma_f32_16x16x32_f16(af[mt], bf[nt], acc[mt][nt], 0, 0, 0);
        }
        __syncthreads();
    }

    // epilogue: C/D layout col=lane&15, row=q*4+reg. Tile -> LDS (stride 136).
#pragma unroll
    for (int nt = 0; nt < 4; ++nt) {
        const int cl = wn * 64 + nt * 16 + mm;
        const int gcol = c0 + cl;
        float s = 0.f, ss = 0.f;
#pragma unroll
        for (int mt = 0; mt < 4; ++mt) {
#pragma unroll
            for (int r = 0; r < 4; ++r) {
                int row = wm * 64 + mt * 16 + q * 4 + r;
                float v = acc[mt][nt][r] + bias[gcol];
                if (MODE != 1) v = fmaxf(v, 0.f);
                union { u16 u; _Float16 h; } cc; cc.h = (_Float16)v;
                lds[row * 136 + cl] = cc.u;
                if (MODE == 1 && row0 + row < nrows) { s += v; ss += v * v; }
            }
        }
        if (MODE == 1) {
            s += __shfl_xor(s, 16);  s += __shfl_xor(s, 32);
            ss += __shfl_xor(ss, 16); ss += __shfl_xor(ss, 32);
            if (q == 0) {
                bnbuf[(wm * 128 + cl) * 2 + 0] = s;
                bnbuf[(wm * 128 + cl) * 2 + 1] = ss;
            }
        }
    }
    __syncthreads();

    if (MODE != 2) {
        int nr = nrows - row0; if (nr > 128) nr = 128;
#pragma unroll
        for (int it = 0; it < 8; ++it) {
            int idx = it * 256 + tid;        // 0..2047 chunks of 16B
            int row = idx >> 4, cp = idx & 15;
            if (row < nr) {
                uint4 v = *(const uint4*)(lds + row * 136 + cp * 8);
                *(uint4*)(outH + (size_t)(row0 + row) * mcols + c0 + cp * 8) = v;
            }
        }
        if (MODE == 1) {
            int cl2 = tid >> 1, comp = tid & 1;
            float v = bnbuf[cl2 * 2 + comp] + bnbuf[(128 + cl2) * 2 + comp];
            partial[(size_t)blockIdx.x * 512 + comp * 256 + c0 + cl2] = v;
        }
    } else {
        // fused head: q-tile (128x128, stride 136) @ wh2 (48-padded) + softmax
        const bool c2ok = (mm < 8);
        float b0 = bh2[mm], b1 = bh2[16 + mm];
        float b2 = c2ok ? bh2[32 + mm] : 0.f;
#pragma unroll
        for (int half = 0; half < 2; ++half) {
            int rbase = half * 64 + wave * 16;    // 16-node group
            f32x4 hacc[3];
#pragma unroll
            for (int t = 0; t < 3; ++t) hacc[t] = (f32x4){0.f, 0.f, 0.f, 0.f};
#pragma unroll
            for (int c = 0; c < 4; ++c) {
                half8 a = *(const half8*)(lds + (rbase + mm) * 136 + c * 32 + q * 8);
#pragma unroll
                for (int t = 0; t < 3; ++t) {
                    half8 b = *(const half8*)(wh2 + ((size_t)(c * 4 + q) * 48 + t * 16 + mm) * 8);
                    hacc[t] = __builtin_amdgcn_mfma_f32_16x16x32_f16(a, b, hacc[t], 0, 0, 0);
                }
            }
#pragma unroll
            for (int r = 0; r < 4; ++r) {
                int node = row0 + rbase + q * 4 + r;
                float v0 = hacc[0][r] + b0;
                float v1 = hacc[1][r] + b1;
                float v2 = c2ok ? (hacc[2][r] + b2) : -3e38f;
                float m = fmaxf(fmaxf(v0, v1), v2);
                m = fmaxf(m, __shfl_xor(m, 1)); m = fmaxf(m, __shfl_xor(m, 2));
                m = fmaxf(m, __shfl_xor(m, 4)); m = fmaxf(m, __shfl_xor(m, 8));
                float e0 = expf(v0 - m), e1 = expf(v1 - m);
                float e2 = c2ok ? expf(v2 - m) : 0.f;
                float s = e0 + e1 + e2;
                s += __shfl_xor(s, 1); s += __shfl_xor(s, 2);
                s += __shfl_xor(s, 4); s += __shfl_xor(s, 8);
                float is = 1.f / s;
                if (node < nrows) {
                    float* op = outF + (size_t)node * 40;
                    op[mm] = e0 * is;
                    op[16 + mm] = e1 * is;
                    if (c2ok) op[32 + mm] = e2 * is;
                }
            }
        }
    }
}

// ===========================================================================
// bnred_k: 16 blocks reduce partial -> bnsum (atomics, 16 contenders/addr);
// last-done block computes final alpha/shift into ab. No spinners.
// ===========================================================================

__global__ void bnred_k(const float* __restrict__ partial, float* __restrict__ bnsum,
                        const float* __restrict__ gamma, const float* __restrict__ beta,
                        float* __restrict__ ab, int* __restrict__ bnctr, int n, int gx) {
    const int tid = threadIdx.x;
    const int g = blockIdx.x;
    float s = 0.f, qq = 0.f;
    for (int r = g; r < gx; r += 16) {
        s  += partial[(size_t)r * 512 + tid];
        qq += partial[(size_t)r * 512 + 256 + tid];
    }
    atomicAdd(&bnsum[tid], s);
    atomicAdd(&bnsum[256 + tid], qq);
    __threadfence();
    __shared__ int last;
    if (tid == 0) last = (atomicAdd(bnctr, 1) == 15);
    __syncthreads();
    if (!last) return;
    float su = atomicAdd(&bnsum[tid], 0.f);
    float sq = atomicAdd(&bnsum[256 + tid], 0.f);
    float invn = 1.f / (float)n;
    float m = su * invn;
    float al = gamma[tid] * rsqrtf(sq * invn - m * m + 1e-5f);
    ab[tid] = al;
    ab[256 + tid] = beta[tid] - m * al;
}

// ===========================================================================
// updmemb_k: residual update from precomputed ab (+ optional next-layer
// membership). Pure streaming, no cross-block sync.
// ===========================================================================

template <int DOMEMB>
__launch_bounds__(256)
__global__ void updmemb_k(const u16* __restrict__ pre16, const float* __restrict__ ab,
                          u16* __restrict__ h16,
                          const u16* __restrict__ pcB, const float* __restrict__ pccc,
                          u16* __restrict__ mu16, int* __restrict__ bflag, int n) {
    const int tid = threadIdx.x;
    const int lane = tid & 63, wave = tid >> 6;
    const int q = lane >> 4, mm = lane & 15;
    const int n0 = (blockIdx.x * 4 + wave) * 16;
    if (n0 >= n) return;
    const int node = n0 + mm;
    const bool valid = node < n;
    const int nodeC = valid ? node : n - 1;
    const size_t base = (size_t)nodeC * 256 + q * 8;

    half8 v16[8];
#pragma unroll
    for (int b = 0; b < 8; ++b) {
        int c = b * 32 + q * 8;
        float4 alA = *(const float4*)(ab + c);
        float4 alB = *(const float4*)(ab + c + 4);
        float4 shA = *(const float4*)(ab + 256 + c);
        float4 shB = *(const float4*)(ab + 256 + c + 4);
        float aarr[8] = {alA.x, alA.y, alA.z, alA.w, alB.x, alB.y, alB.z, alB.w};
        float harr[8] = {shA.x, shA.y, shA.z, shA.w, shB.x, shB.y, shB.z, shB.w};
        union { uint4 u; _Float16 hh[8]; } p, hv, o;
        p.u  = *(const uint4*)(pre16 + base + b * 32);
        hv.u = *(const uint4*)(h16 + base + b * 32);
#pragma unroll
        for (int j = 0; j < 8; ++j) {
            float v = (float)hv.hh[j] + fmaxf((float)p.hh[j] * aarr[j] + harr[j], 0.f);
            o.hh[j] = (_Float16)v;
        }
        if (valid) *(uint4*)(h16 + base + b * 32) = o.u;
        v16[b] = *(half8*)&o;
    }

    if (DOMEMB) {
        const u16* brow = pcB + (size_t)mm * 512;
        f32x4 acc = (f32x4){0.f, 0.f, 0.f, 0.f};
#pragma unroll
        for (int it = 0; it < 16; ++it) {
            half8 a = v16[it & 7];
            if (it < 8) a = a * a;
            half8 bb = *(const half8*)(brow + it * 32 + q * 8);
            acc = __builtin_amdgcn_mfma_f32_16x16x32_f16(a, bb, acc, 0, 0, 0);
        }
        float cc = pccc[mm];
        bool any = false;
#pragma unroll
        for (int r = 0; r < 4; ++r) {
            float d = acc[r] + cc;
            float f = expf(-0.5f * d);
            float s = f;
            s += __shfl_xor(s, 1); s += __shfl_xor(s, 2);
            s += __shfl_xor(s, 4); s += __shfl_xor(s, 8);
            int nd = n0 + q * 4 + r;
            if (nd < n) {
                union { u16 u; _Float16 h; } c2;
                c2.h = (_Float16)(f / (s + 1e-12f));
                mu16[(size_t)nd * 16 + mm] = c2.u;
                if (s > 0.f) any = true;
            }
        }
        if (any && mm == 0) {
            atomicOr(&bflag[n0 >> 7], 1);
            atomicOr(&bflag[511], 1);
        }
    }
}

// ===========================================================================
// Launch
// ===========================================================================

extern "C" void kernel_launch(void* const* d_in, const int* in_sizes, int n_in,
                              void* d_out, int out_size, void* d_ws, size_t ws_size,
                              hipStream_t stream) {
    const float* x       = (const float*)d_in[0];
    const int*   ei      = (const int*)d_in[1];
    const float* W_in    = (const float*)d_in[2];
    const float* b_in    = (const float*)d_in[3];
    const float* centers = (const float*)d_in[4];
    const float* logsig  = (const float*)d_in[5];
    const float* W_rule  = (const float*)d_in[6];
    const float* b_rule  = (const float*)d_in[7];
    const float* W_self  = (const float*)d_in[8];
    const float* b_self  = (const float*)d_in[9];
    const float* gamma   = (const float*)d_in[10];
    const float* beta    = (const float*)d_in[11];
    const float* W_h1    = (const float*)d_in[12];
    const float* b_h1    = (const float*)d_in[13];
    const float* W_h2    = (const float*)d_in[14];
    const float* b_h2    = (const float*)d_in[15];

    const int N = in_sizes[0] / 128;
    const int E = in_sizes[1] / 2;
    const int* e_src = ei;
    const int* e_dst = ei + E;

    char* w = (char*)d_ws;
    size_t off = 0;
    auto alloc = [&](size_t bytes) -> void* {
        void* p = w + off;
        off = (off + bytes + 255) & ~(size_t)255;
        return p;
    };

    const int gx = cdiv(N, 128);

    u16*   h16    = (u16*)  alloc((size_t)N * 256 * 2);
    u16*   pre16  = (u16*)  alloc((size_t)N * 256 * 2);
    u16*   agg16  = (u16*)  alloc((size_t)N * 256 * 2);
    u16*   mu16   = (u16*)  alloc((size_t)N * 16 * 2);
    u16*   wcat   = (u16*)  alloc((size_t)3 * 552 * 256 * 8 * 2);
    u16*   winp   = (u16*)  alloc((size_t)16 * 256 * 8 * 2);
    u16*   wh1p   = (u16*)  alloc((size_t)32 * 128 * 8 * 2);
    u16*   wh2p   = (u16*)  alloc((size_t)16 * 48 * 8 * 2);
    u16*   pcB    = (u16*)  alloc((size_t)48 * 512 * 2);
    float* pccc   = (float*)alloc((size_t)48 * 4);
    int*   indptr = (int*)  alloc((size_t)(N + 1) * 4);
    int*   cursor = (int*)  alloc((size_t)N * 4);
    float* deginv = (float*)alloc((size_t)N * 4);
    int*   ssrc   = (int*)  alloc((size_t)E * 4);
    float* partial= (float*)alloc((size_t)gx * 512 * 4);
    float* abA    = (float*)alloc((size_t)3 * 512 * 4);
    // zero region: [deg N][bflag 3*512][bnsum 3*512][done, csrctr, bnctr[3]]
    const int nzero = N + 3 * 512 + 3 * 512 + 16;
    int*   zerob  = (int*)  alloc((size_t)nzero * 4);
    int*   deg    = zerob;
    int*   bflagA = zerob + N;
    float* bnsumA = (float*)(zerob + N + 3 * 512);
    int*   misc   = zerob + N + 3 * 512 + 3 * 512;
    int*   done   = misc;
    int*   csrctr = misc + 1;
    int*   bnctr  = misc + 2;   // [3]

    const int Z = cdiv(nzero, 256);
    const int Wb = 3 * 552 * 256 * 8 / 256;   // 13248
    const int prep_grid = Z + Wb + 128 + 128 + 24 + 48;

    prep_k<<<prep_grid, 256, 0, stream>>>(W_rule, W_self, b_rule, W_in, W_h1, W_h2,
                                          centers, logsig, wcat, winp, wh1p, wh2p,
                                          pcB, pccc, zerob, nzero, Z, Wb);

    gemm_k<0, 2><<<dim3(gx, 2), 256, 0, stream>>>((const u16*)x, nullptr, nullptr, winp,
                                                  b_in, nullptr, h16, nullptr, nullptr,
                                                  nullptr, nullptr, N, 256, 128);
    memb_k<<<cdiv(N, 64), 256, 0, stream>>>(h16, pcB, pccc, mu16, bflagA, N);

    for (int l = 0; l < 3; ++l) {
        int* bf = bflagA + l * 512;
        float* bns = bnsumA + l * 512;
        float* ab = abA + l * 512;
        csr_agg_g<<<256, 256, 0, stream>>>(e_src, e_dst, deg, indptr, cursor, deginv,
                                           ssrc, csrctr, bf, done, h16, agg16, E, N);
        gemm_k<1, 69><<<dim3(gx, 2), 256, 0, stream>>>(agg16, h16, mu16,
                                                       wcat + (size_t)l * 552 * 256 * 8,
                                                       b_self + l * 256, bf, pre16,
                                                       partial, nullptr, nullptr, nullptr,
                                                       N, 256, 0);
        bnred_k<<<16, 256, 0, stream>>>(partial, bns, gamma + l * 256, beta + l * 256,
                                        ab, bnctr + l, N, gx);
        if (l < 2) {
            updmemb_k<1><<<cdiv(N, 64), 256, 0, stream>>>(pre16, ab, h16,
                                                          pcB + (size_t)(l + 1) * 16 * 512,
                                                          pccc + (l + 1) * 16, mu16,
                                                          bflagA + (l + 1) * 512, N);
        } else {
            updmemb_k<0><<<cdiv(N, 64), 256, 0, stream>>>(pre16, ab, h16,
                                                          nullptr, nullptr, nullptr,
                                                          nullptr, N);
        }
    }

    gemm_k<2, 4><<<dim3(gx, 1), 256, 0, stream>>>(h16, nullptr, nullptr, wh1p, b_h1,
                                                  nullptr, nullptr, nullptr, wh2p, b_h2,
                                                  (float*)d_out, N, 128, 256);
}